// Round 1
// baseline (9676.450 us; speedup 1.0000x reference)
//
#include <hip/hip_runtime.h>
#include <math.h>

// Problem dims
constexpr int Bb   = 4;
constexpr int Cch  = 512;
constexpr int Tt   = 4;
constexpr int H0c  = 63, W0c = 63;
constexpr int Hp   = 31, Wp  = 31;
constexpr int HW   = 961;      // 31*31
constexpr int THW  = 3844;     // 4*961
constexpr int CC   = 256;      // attention channels
constexpr int NCMP = 126;      // 3*42 compare channels
constexpr int AGGK = 1016;
constexpr int NPIX = Bb * Cch * Tt * HW;  // 7,872,512 (xp / Z / out elements)
#define BN_EPS 1e-5f

// ---------------- K1: maxpool (1,3,3)/(1,2,2) ----------------
__global__ __launch_bounds__(256) void k_pool(const float* __restrict__ x,
                                              float* __restrict__ xp) {
    int idx = blockIdx.x * 256 + threadIdx.x;
    if (idx >= NPIX) return;
    int w = idx % Wp;
    int h = (idx / Wp) % Hp;
    int bct = idx / HW;  // (b*512+c)*4+t
    const float* src = x + (size_t)bct * (H0c * W0c) + (2 * h) * W0c + 2 * w;
    float m = -INFINITY;
    #pragma unroll
    for (int i = 0; i < 3; ++i) {
        m = fmaxf(m, src[i * W0c + 0]);
        m = fmaxf(m, src[i * W0c + 1]);
        m = fmaxf(m, src[i * W0c + 2]);
    }
    xp[idx] = m;
}

// ---------------- K2: Q/M/V projections (tiled fp32 GEMM) ----------------
// Out[oc,p] = sum_k W[oc,k] * xp[b,k,p].  Q/M/V channel-last; V also channel-first.
__global__ __launch_bounds__(256) void k_qmv(
    const float* __restrict__ xp, const float* __restrict__ Wq,
    const float* __restrict__ Wm, const float* __restrict__ Wv,
    float* __restrict__ Qcl, float* __restrict__ Mcl,
    float* __restrict__ Vcl, float* __restrict__ Vcf) {
    __shared__ float Wt[16][64];  // [k][oc]
    __shared__ float Xt[16][64];  // [k][p]
    const int p0  = blockIdx.x * 64;
    const int oc0 = blockIdx.y * 64;
    const int b   = blockIdx.z;
    const int sel = oc0 >> 8;          // 0:Q 1:M 2:V
    const int ocr = oc0 & 255;
    const float* Wbase = (sel == 0) ? Wq : (sel == 1) ? Wm : Wv;
    const int tx = threadIdx.x, ty = threadIdx.y;
    const int tid = ty * 16 + tx;
    float acc[4][4] = {{0.f}};
    for (int kc = 0; kc < 512; kc += 16) {
        __syncthreads();
        for (int l = tid; l < 1024; l += 256) {
            int kk = l & 15, j = l >> 4;
            Wt[kk][j] = Wbase[(size_t)(ocr + j) * 512 + kc + kk];
        }
        for (int l = tid; l < 1024; l += 256) {
            int pp = l & 63, kk = l >> 6;
            int p = p0 + pp;
            Xt[kk][pp] = (p < THW) ? xp[(size_t)(b * Cch + kc + kk) * THW + p] : 0.f;
        }
        __syncthreads();
        #pragma unroll
        for (int kk = 0; kk < 16; ++kk) {
            float a[4], c[4];
            *(float4*)a = *(const float4*)&Wt[kk][ty * 4];
            *(float4*)c = *(const float4*)&Xt[kk][tx * 4];
            #pragma unroll
            for (int i = 0; i < 4; ++i)
                #pragma unroll
                for (int j = 0; j < 4; ++j) acc[i][j] = fmaf(a[i], c[j], acc[i][j]);
        }
    }
    float* outcl = (sel == 0) ? Qcl : (sel == 1) ? Mcl : Vcl;
    const int ocl = ocr + ty * 4;
    #pragma unroll
    for (int j = 0; j < 4; ++j) {
        int p = p0 + tx * 4 + j;
        if (p < THW) {
            float4 v = make_float4(acc[0][j], acc[1][j], acc[2][j], acc[3][j]);
            *(float4*)&outcl[((size_t)b * THW + p) * 256 + ocl] = v;
        }
    }
    if (sel == 2) {
        int pb = p0 + tx * 4;
        if (pb < THW) {
            #pragma unroll
            for (int i = 0; i < 4; ++i) {
                float4 v = make_float4(acc[i][0], acc[i][1], acc[i][2], acc[i][3]);
                *(float4*)&Vcf[((size_t)b * 256 + ocl + i) * THW + pb] = v;
            }
        }
    }
}

// ---------------- K3: attention (scores+softmax+PV), 8 queries/block ----------------
// R[b,m,q,c] = sum_j softmax_j(Q[b,q,:].M[b,m*961+j,:]/16) * V[b,m*961+j,c]
__global__ __launch_bounds__(256) void k_attn(const float* __restrict__ Q,
                                              const float* __restrict__ M,
                                              const float* __restrict__ V,
                                              float* __restrict__ R) {
    __shared__ float Qs[8][260];   // +4 pad: q-rows land in distinct banks
    __shared__ float S[8][968];    // score strip, stride 968 (8-bank row offset)
    const int qt = blockIdx.x, m = blockIdx.y, b = blockIdx.z;
    const int q0 = qt * 8;
    const int tid = threadIdx.x;
    // load Q tile (zero-fill OOB rows)
    for (int l = tid; l < 512; l += 256) {
        int r = l >> 6, c4 = (l & 63) * 4;
        int q = q0 + r;
        float4 v = make_float4(0.f, 0.f, 0.f, 0.f);
        if (q < THW) v = *(const float4*)&Q[((size_t)b * THW + q) * 256 + c4];
        *(float4*)&Qs[r][c4] = v;
    }
    __syncthreads();
    const int q = tid >> 5, jl = tid & 31;
    const size_t mvbase = ((size_t)b * THW + m * HW) * 256;
    // phase 1: scores
    for (int jj = 0; jj < 31; ++jj) {
        int j = jj * 32 + jl;
        if (j < HW) {
            const float* mrow = M + mvbase + (size_t)j * 256;
            float s0 = 0.f, s1 = 0.f, s2 = 0.f, s3 = 0.f;
            #pragma unroll 8
            for (int c = 0; c < 256; c += 4) {
                float4 mv = *(const float4*)&mrow[c];
                float4 qv = *(const float4*)&Qs[q][c];
                s0 = fmaf(mv.x, qv.x, s0); s1 = fmaf(mv.y, qv.y, s1);
                s2 = fmaf(mv.z, qv.z, s2); s3 = fmaf(mv.w, qv.w, s3);
            }
            S[q][j] = (s0 + s1 + s2 + s3) * 0.0625f;
        }
    }
    // phase 2: softmax over the 961 keys of this memory frame (32 lanes per q-row)
    float mx = -1e30f;
    for (int j = jl; j < HW; j += 32) mx = fmaxf(mx, S[q][j]);
    #pragma unroll
    for (int off = 16; off > 0; off >>= 1) mx = fmaxf(mx, __shfl_xor(mx, off, 32));
    float sum = 0.f;
    for (int j = jl; j < HW; j += 32) {
        float e = __expf(S[q][j] - mx);
        S[q][j] = e;
        sum += e;
    }
    #pragma unroll
    for (int off = 16; off > 0; off >>= 1) sum += __shfl_xor(sum, off, 32);
    const float inv = 1.f / sum;
    __syncthreads();
    // phase 3: R accumulate; lane owns 8 channels cb..cb+7
    const int cb = jl * 8;
    float acc[8] = {0.f, 0.f, 0.f, 0.f, 0.f, 0.f, 0.f, 0.f};
    const float* vbase = V + mvbase + cb;
    #pragma unroll 2
    for (int j = 0; j < HW; ++j) {
        float w = S[q][j];  // broadcast within q-group
        const float* vrow = vbase + (size_t)j * 256;
        float4 v0 = *(const float4*)&vrow[0];
        float4 v1 = *(const float4*)&vrow[4];
        acc[0] = fmaf(w, v0.x, acc[0]); acc[1] = fmaf(w, v0.y, acc[1]);
        acc[2] = fmaf(w, v0.z, acc[2]); acc[3] = fmaf(w, v0.w, acc[3]);
        acc[4] = fmaf(w, v1.x, acc[4]); acc[5] = fmaf(w, v1.y, acc[5]);
        acc[6] = fmaf(w, v1.z, acc[6]); acc[7] = fmaf(w, v1.w, acc[7]);
    }
    int qq = q0 + q;
    if (qq < THW) {
        float* rrow = R + ((size_t)(b * 4 + m) * THW + qq) * 256 + cb;
        *(float4*)&rrow[0] = make_float4(acc[0] * inv, acc[1] * inv, acc[2] * inv, acc[3] * inv);
        *(float4*)&rrow[4] = make_float4(acc[4] * inv, acc[5] * inv, acc[6] * inv, acc[7] * inv);
    }
}

// ---------------- K4: Rmean (mean over query-frame) + transpose to channel-first ----
// Rm[b,c,m*961+hw] = 0.25*sum_tq R[b,m,tq*961+hw,c]
__global__ __launch_bounds__(256) void k_rmean(const float* __restrict__ R,
                                               float* __restrict__ Rm) {
    __shared__ float tile[32][33];
    const int hw0 = blockIdx.x * 32, c0 = blockIdx.y * 32;
    const int bm = blockIdx.z, b = bm >> 2, m = bm & 3;
    const int tid = threadIdx.x;
    float acc[4] = {0.f, 0.f, 0.f, 0.f};
    #pragma unroll
    for (int tq = 0; tq < 4; ++tq) {
        const size_t base = ((size_t)(b * 4 + m) * THW + tq * HW) * 256;
        #pragma unroll
        for (int k = 0; k < 4; ++k) {
            int l = tid + k * 256;
            int hwl = l >> 5, cl = l & 31;
            if (hw0 + hwl < HW) acc[k] += R[base + (size_t)(hw0 + hwl) * 256 + c0 + cl];
        }
    }
    #pragma unroll
    for (int k = 0; k < 4; ++k) {
        int l = tid + k * 256;
        tile[l >> 5][l & 31] = acc[k] * 0.25f;
    }
    __syncthreads();
    #pragma unroll
    for (int k = 0; k < 4; ++k) {
        int l = tid + k * 256;
        int cl = l >> 5, hwl = l & 31;
        if (hw0 + hwl < HW)
            Rm[((size_t)b * 256 + c0 + cl) * THW + m * HW + hw0 + hwl] = tile[hwl][cl];
    }
}

// ---------------- K5: compare branch convs (pre-BN), channel-first output --------
// Pc[b, ci, s=m*4+tq, hw]; ci: 0-41 cat, 42-83 sub, 84-125 mul
__global__ __launch_bounds__(256) void k_compare(
    const float* __restrict__ R, const float* __restrict__ V,
    const float* __restrict__ Wcat, const float* __restrict__ Wsub,
    const float* __restrict__ Wmul, float* __restrict__ Pc) {
    __shared__ float Rt[31][257];
    __shared__ float Vt[31][257];
    const int hw0 = blockIdx.x * 31, s = blockIdx.y, b = blockIdx.z;
    const int m = s >> 2, tq = s & 3;
    const int tid = threadIdx.x;
    const size_t rbase = ((size_t)(b * 4 + m) * THW + tq * HW + hw0) * 256;
    const size_t vbase = ((size_t)b * THW + m * HW + hw0) * 256;
    for (int l = tid; l < 31 * 64; l += 256) {
        int row = l >> 6, c4 = (l & 63) * 4;
        float4 rv = *(const float4*)&R[rbase + (size_t)row * 256 + c4];
        float4 vv = *(const float4*)&V[vbase + (size_t)row * 256 + c4];
        Rt[row][c4 + 0] = rv.x; Rt[row][c4 + 1] = rv.y; Rt[row][c4 + 2] = rv.z; Rt[row][c4 + 3] = rv.w;
        Vt[row][c4 + 0] = vv.x; Vt[row][c4 + 1] = vv.y; Vt[row][c4 + 2] = vv.z; Vt[row][c4 + 3] = vv.w;
    }
    __syncthreads();
    const int px = tid & 31, g = tid >> 5;
    if (px < 31) {
        for (int kk = 0; kk < 16; ++kk) {
            int ci = g + (kk << 3);
            if (ci >= NCMP) break;
            float acc = 0.f;
            if (ci < 42) {
                const float* wr = Wcat + (size_t)ci * 512;
                #pragma unroll 4
                for (int k = 0; k < 256; ++k)
                    acc += wr[k] * Rt[px][k] + wr[256 + k] * Vt[px][k];
            } else if (ci < 84) {
                const float* wr = Wsub + (size_t)(ci - 42) * 256;
                #pragma unroll 4
                for (int k = 0; k < 256; ++k) acc += wr[k] * (Rt[px][k] - Vt[px][k]);
            } else {
                const float* wr = Wmul + (size_t)(ci - 84) * 256;
                #pragma unroll 4
                for (int k = 0; k < 256; ++k) acc += wr[k] * (Rt[px][k] * Vt[px][k]);
            }
            Pc[((size_t)(b * NCMP + ci) * 16 + s) * HW + hw0 + px] = acc;
        }
    }
}

// ---------------- K6: BN stats for compare branches ----------------
__global__ __launch_bounds__(256) void k_stats_cmp(
    const float* __restrict__ Pc, const float* __restrict__ g_cat,
    const float* __restrict__ b_cat, const float* __restrict__ g_sub,
    const float* __restrict__ b_sub, const float* __restrict__ g_mul,
    const float* __restrict__ b_mul, float* __restrict__ bnc) {
    const int c = blockIdx.x, tid = threadIdx.x;
    float s = 0.f, q = 0.f;
    for (int i = tid; i < 4 * 16 * HW; i += 256) {
        int bb = i / (16 * HW), r = i - bb * (16 * HW);
        float v = Pc[(size_t)(bb * NCMP + c) * (16 * HW) + r];
        s += v; q += v * v;
    }
    __shared__ float rs[256], rq[256];
    rs[tid] = s; rq[tid] = q;
    __syncthreads();
    for (int off = 128; off > 0; off >>= 1) {
        if (tid < off) { rs[tid] += rs[tid + off]; rq[tid] += rq[tid + off]; }
        __syncthreads();
    }
    if (tid == 0) {
        const float n = 4.f * 16.f * HW;
        float mean = rs[0] / n;
        float var = rq[0] / n - mean * mean;
        float g, bt;
        if (c < 42)       { g = g_cat[c];      bt = b_cat[c]; }
        else if (c < 84)  { g = g_sub[c - 42]; bt = b_sub[c - 42]; }
        else              { g = g_mul[c - 84]; bt = b_mul[c - 84]; }
        float sc = g * rsqrtf(var + BN_EPS);
        bnc[c] = sc;
        bnc[NCMP + c] = bt - mean * sc;
    }
}

// ---------------- K7: aggregate GEMM (Y gathered on the fly) ----------------
// Z[b,oc,p] = sum_ic Wagg[oc,ic] * Y[b,ic,p]
__global__ __launch_bounds__(256) void k_agg(
    const float* __restrict__ Wagg, const float* __restrict__ Rm,
    const float* __restrict__ Vcf, const float* __restrict__ Pc,
    const float* __restrict__ bnc, float* __restrict__ Z) {
    __shared__ float Wt[16][64];
    __shared__ float Yt[16][64];
    const int p0 = blockIdx.x * 64, oc0 = blockIdx.y * 64, b = blockIdx.z;
    const int tx = threadIdx.x, ty = threadIdx.y;
    const int tid = ty * 16 + tx;
    float acc[4][4] = {{0.f}};
    for (int kc = 0; kc < AGGK; kc += 16) {
        __syncthreads();
        for (int l = tid; l < 1024; l += 256) {
            int kk = l & 15, j = l >> 4;
            int ic = kc + kk;
            Wt[kk][j] = (ic < AGGK) ? Wagg[(size_t)(oc0 + j) * AGGK + ic] : 0.f;
        }
        for (int l = tid; l < 1024; l += 256) {
            int pp = l & 63, kk = l >> 6;
            int ic = kc + kk, p = p0 + pp;
            float v = 0.f;
            if (p < THW && ic < AGGK) {
                if (ic < 256) v = Rm[((size_t)b * 256 + ic) * THW + p];
                else if (ic < 512) v = Vcf[((size_t)b * 256 + (ic - 256)) * THW + p];
                else {
                    int j2 = ic - 512;
                    int co = j2 >> 2, mm = j2 & 3;
                    int tq = p / HW, hw = p - tq * HW;
                    float pv = Pc[((size_t)(b * NCMP + co) * 16 + (mm * 4 + tq)) * HW + hw];
                    v = fmaxf(fmaf(pv, bnc[co], bnc[NCMP + co]), 0.f);
                }
            }
            Yt[kk][pp] = v;
        }
        __syncthreads();
        #pragma unroll
        for (int kk = 0; kk < 16; ++kk) {
            float a[4], c[4];
            *(float4*)a = *(const float4*)&Wt[kk][ty * 4];
            *(float4*)c = *(const float4*)&Yt[kk][tx * 4];
            #pragma unroll
            for (int i = 0; i < 4; ++i)
                #pragma unroll
                for (int j = 0; j < 4; ++j) acc[i][j] = fmaf(a[i], c[j], acc[i][j]);
        }
    }
    const int oc = oc0 + ty * 4;
    const int pb = p0 + tx * 4;
    if (pb < THW) {
        #pragma unroll
        for (int i = 0; i < 4; ++i) {
            float4 v = make_float4(acc[i][0], acc[i][1], acc[i][2], acc[i][3]);
            *(float4*)&Z[((size_t)b * Cch + oc + i) * THW + pb] = v;
        }
    }
}

// ---------------- K8: BN stats for aggregate ----------------
__global__ __launch_bounds__(256) void k_stats_agg(
    const float* __restrict__ Z, const float* __restrict__ g_agg,
    const float* __restrict__ b_agg, float* __restrict__ bna) {
    const int c = blockIdx.x, tid = threadIdx.x;
    float s = 0.f, q = 0.f;
    for (int i = tid; i < 4 * THW; i += 256) {
        int bb = i / THW, p = i - bb * THW;
        float v = Z[((size_t)bb * Cch + c) * THW + p];
        s += v; q += v * v;
    }
    __shared__ float rs[256], rq[256];
    rs[tid] = s; rq[tid] = q;
    __syncthreads();
    for (int off = 128; off > 0; off >>= 1) {
        if (tid < off) { rs[tid] += rs[tid + off]; rq[tid] += rq[tid + off]; }
        __syncthreads();
    }
    if (tid == 0) {
        const float n = 4.f * THW;
        float mean = rs[0] / n;
        float var = rq[0] / n - mean * mean;
        float sc = g_agg[c] * rsqrtf(var + BN_EPS);
        bna[c] = sc;
        bna[Cch + c] = b_agg[c] - mean * sc;
    }
}

// ---------------- K9: out = relu(xp + BN(Z)) ----------------
__global__ __launch_bounds__(256) void k_final(const float* __restrict__ xp,
                                               const float* __restrict__ Z,
                                               const float* __restrict__ bna,
                                               float* __restrict__ out) {
    int idx = blockIdx.x * 256 + threadIdx.x;
    if (idx >= NPIX) return;
    int c = (idx / THW) & 511;
    out[idx] = fmaxf(fmaf(Z[idx], bna[c], bna[Cch + c]) + xp[idx], 0.f);
}

extern "C" void kernel_launch(void* const* d_in, const int* in_sizes, int n_in,
                              void* d_out, int out_size, void* d_ws, size_t ws_size,
                              hipStream_t stream) {
    const float* x     = (const float*)d_in[0];
    const float* Wq    = (const float*)d_in[1];
    const float* Wm    = (const float*)d_in[2];
    const float* Wv    = (const float*)d_in[3];
    const float* Wcat  = (const float*)d_in[4];
    const float* Wsub  = (const float*)d_in[5];
    const float* Wmul  = (const float*)d_in[6];
    const float* g_cat = (const float*)d_in[7];
    const float* b_cat = (const float*)d_in[8];
    const float* g_sub = (const float*)d_in[9];
    const float* b_sub = (const float*)d_in[10];
    const float* g_mul = (const float*)d_in[11];
    const float* b_mul = (const float*)d_in[12];
    const float* Wagg  = (const float*)d_in[13];
    const float* g_agg = (const float*)d_in[14];
    const float* b_agg = (const float*)d_in[15];
    float* out = (float*)d_out;
    float* ws  = (float*)d_ws;

    // workspace layout (floats); total 47,114,752 floats = 188.5 MB
    float* xp  = ws;                 // 7,872,512
    float* Q   = xp  + 7872512;      // 3,936,256 (channel-last)
    float* M   = Q   + 3936256;      // 3,936,256
    float* Vcl = M   + 3936256;      // 3,936,256
    float* Vcf = Vcl + 3936256;      // 3,936,256
    float* R   = Vcf + 3936256;      // 15,745,024 (b,m,q,c channel-last)
    float* Pc  = R   + 15745024;     // 7,750,656 (channel-first)
    float* bnc = Pc  + 7750656;      // 512 (scale[126], shift[126])
    float* bna = bnc + 512;          // 1024 (scale[512], shift[512])
    float* Rm  = Q;                  // alias: Q dead after attention
    float* Z   = R;                  // alias: R dead after rmean+compare

    k_pool<<<dim3((NPIX + 255) / 256), dim3(256), 0, stream>>>(x, xp);
    k_qmv<<<dim3(61, 12, Bb), dim3(16, 16), 0, stream>>>(xp, Wq, Wm, Wv, Q, M, Vcl, Vcf);
    k_attn<<<dim3(481, 4, Bb), dim3(256), 0, stream>>>(Q, M, Vcl, R);
    k_rmean<<<dim3(31, 8, 16), dim3(256), 0, stream>>>(R, Rm);
    k_compare<<<dim3(31, 16, Bb), dim3(256), 0, stream>>>(R, Vcl, Wcat, Wsub, Wmul, Pc);
    k_stats_cmp<<<dim3(NCMP), dim3(256), 0, stream>>>(Pc, g_cat, b_cat, g_sub, b_sub,
                                                      g_mul, b_mul, bnc);
    k_agg<<<dim3(61, 8, Bb), dim3(16, 16), 0, stream>>>(Wagg, Rm, Vcf, Pc, bnc, Z);
    k_stats_agg<<<dim3(Cch), dim3(256), 0, stream>>>(Z, g_agg, b_agg, bna);
    k_final<<<dim3((NPIX + 255) / 256), dim3(256), 0, stream>>>(xp, Z, bna, out);
}

// Round 2
// 2257.972 us; speedup vs baseline: 4.2855x; 4.2855x over previous
//
#include <hip/hip_runtime.h>
#include <math.h>

// Problem dims
constexpr int Bb   = 4;
constexpr int Cch  = 512;
constexpr int HW   = 961;      // 31*31
constexpr int THW  = 3844;     // 4*961
constexpr int NCMP = 126;      // 3*42 compare channels
constexpr int AGGK = 1016;
constexpr int NPIX = Bb * Cch * THW;  // 7,872,512
constexpr int Hp = 31, Wp = 31, H0c = 63, W0c = 63;
constexpr int VP = 968;        // padded keys/frame for Vbf (8B-aligned ushort4)
#define BN_EPS 1e-5f

typedef __attribute__((ext_vector_type(4))) float floatx4;
typedef __attribute__((ext_vector_type(8))) __bf16 bf16x8;
typedef __attribute__((ext_vector_type(8))) unsigned short ushort8;
typedef __attribute__((ext_vector_type(4))) unsigned short ushort4v;

static __device__ __forceinline__ unsigned short f2bf(float x) {
    unsigned int u = __builtin_bit_cast(unsigned int, x);
    u += 0x7fff + ((u >> 16) & 1);   // RNE
    return (unsigned short)(u >> 16);
}

// ---------------- K1: maxpool (1,3,3)/(1,2,2) ----------------
__global__ __launch_bounds__(256) void k_pool(const float* __restrict__ x,
                                              float* __restrict__ xp) {
    int idx = blockIdx.x * 256 + threadIdx.x;
    if (idx >= NPIX) return;
    int w = idx % Wp;
    int h = (idx / Wp) % Hp;
    int bct = idx / HW;
    const float* src = x + (size_t)bct * (H0c * W0c) + (2 * h) * W0c + 2 * w;
    float m = -INFINITY;
    #pragma unroll
    for (int i = 0; i < 3; ++i) {
        m = fmaxf(m, src[i * W0c + 0]);
        m = fmaxf(m, src[i * W0c + 1]);
        m = fmaxf(m, src[i * W0c + 2]);
    }
    xp[idx] = m;
}

// ---------------- K2: Q/M/V projections (tiled fp32 GEMM, bf16 side outputs) ----
// Qbf: [b][p][ch] bf16 pre-scaled by 1/16. Mbf: [b][p][ch] bf16.
// Vcl: [b][p][ch] fp32 (compare). Vcf: [b][ch][p] fp32 (aggregate).
// Vbf: [b][m][ch][key(968 pad)] bf16 (attention).
__global__ __launch_bounds__(256) void k_qmv(
    const float* __restrict__ xp, const float* __restrict__ Wq,
    const float* __restrict__ Wm, const float* __restrict__ Wv,
    unsigned short* __restrict__ Qbf, unsigned short* __restrict__ Mbf,
    float* __restrict__ Vcl, float* __restrict__ Vcf,
    unsigned short* __restrict__ Vbf) {
    __shared__ float Wt[16][64];
    __shared__ float Xt[16][64];
    const int p0  = blockIdx.x * 64;
    const int oc0 = blockIdx.y * 64;
    const int b   = blockIdx.z;
    const int sel = oc0 >> 8;          // 0:Q 1:M 2:V
    const int ocr = oc0 & 255;
    const float* Wbase = (sel == 0) ? Wq : (sel == 1) ? Wm : Wv;
    const int tx = threadIdx.x, ty = threadIdx.y;
    const int tid = ty * 16 + tx;
    float acc[4][4] = {{0.f}};
    for (int kc = 0; kc < 512; kc += 16) {
        __syncthreads();
        for (int l = tid; l < 1024; l += 256) {
            int kk = l & 15, j = l >> 4;
            Wt[kk][j] = Wbase[(size_t)(ocr + j) * 512 + kc + kk];
        }
        for (int l = tid; l < 1024; l += 256) {
            int pp = l & 63, kk = l >> 6;
            int p = p0 + pp;
            Xt[kk][pp] = (p < THW) ? xp[(size_t)(b * Cch + kc + kk) * THW + p] : 0.f;
        }
        __syncthreads();
        #pragma unroll
        for (int kk = 0; kk < 16; ++kk) {
            float a[4], c[4];
            *(float4*)a = *(const float4*)&Wt[kk][ty * 4];
            *(float4*)c = *(const float4*)&Xt[kk][tx * 4];
            #pragma unroll
            for (int i = 0; i < 4; ++i)
                #pragma unroll
                for (int j = 0; j < 4; ++j) acc[i][j] = fmaf(a[i], c[j], acc[i][j]);
        }
    }
    const int ocl = ocr + ty * 4;
    if (sel < 2) {
        unsigned short* outbf = (sel == 0) ? Qbf : Mbf;
        const float scale = (sel == 0) ? 0.0625f : 1.0f;
        #pragma unroll
        for (int j = 0; j < 4; ++j) {
            int p = p0 + tx * 4 + j;
            if (p < THW) {
                ushort4v v;
                #pragma unroll
                for (int i = 0; i < 4; ++i) v[i] = f2bf(acc[i][j] * scale);
                *(ushort4v*)&outbf[((size_t)b * THW + p) * 256 + ocl] = v;
            }
        }
    } else {
        #pragma unroll
        for (int j = 0; j < 4; ++j) {
            int p = p0 + tx * 4 + j;
            if (p < THW) {
                float4 v = make_float4(acc[0][j], acc[1][j], acc[2][j], acc[3][j]);
                *(float4*)&Vcl[((size_t)b * THW + p) * 256 + ocl] = v;
            }
        }
        int pb = p0 + tx * 4;
        if (pb < THW) {
            #pragma unroll
            for (int i = 0; i < 4; ++i) {
                float4 v = make_float4(acc[i][0], acc[i][1], acc[i][2], acc[i][3]);
                *(float4*)&Vcf[((size_t)b * 256 + ocl + i) * THW + pb] = v;
            }
            #pragma unroll
            for (int j = 0; j < 4; ++j) {
                int p = pb + j;
                int mm = p / HW, key = p - mm * HW;
                #pragma unroll
                for (int i = 0; i < 4; ++i)
                    Vbf[(((size_t)(b * 4 + mm)) * 256 + ocl + i) * VP + key] =
                        f2bf(acc[i][j]);
            }
        }
    }
}

// ---------------- K3: flash attention, bf16 MFMA ----------------
// Per block: 64 queries x one memory frame. R[b][m][q][ch] fp32.
__global__ __launch_bounds__(256, 2) void k_attn_mfma(
    const unsigned short* __restrict__ Qbf, const unsigned short* __restrict__ Mbf,
    const unsigned short* __restrict__ Vbf, float* __restrict__ R) {
    // LDS: MV union 32768B + S 17152B + Ps 8192B + stats 768B = 58,880B -> 2 blocks/CU
    __shared__ unsigned short MV[16384] __attribute__((aligned(16)));  // Mt[64][256] | Vt[256][64], XOR-swizzled chunks
    __shared__ unsigned short Ps[4096] __attribute__((aligned(16)));   // [64][64] swizzled
    __shared__ float S[64 * 67];
    __shared__ float m_s[64], l_s[64], alpha_s[64];

    const int q0 = blockIdx.x * 64;
    const int m  = blockIdx.y, b = blockIdx.z;
    const int tid = threadIdx.x;
    const int wv = tid >> 6, lane = tid & 63;
    const int l15 = lane & 15, quad = lane >> 4;

    if (tid < 64) { m_s[tid] = -1e30f; l_s[tid] = 0.f; }

    // Q fragments in registers: 4 m-tiles x 8 k-steps (K=256), reused all 16 key-tiles
    ushort8 qf[4][8];
    #pragma unroll
    for (int mt = 0; mt < 4; ++mt) {
        int q = q0 + mt * 16 + l15;
        #pragma unroll
        for (int kci = 0; kci < 8; ++kci) {
            ushort8 v = {0, 0, 0, 0, 0, 0, 0, 0};
            if (q < THW)
                v = *(const ushort8*)&Qbf[((size_t)b * THW + q) * 256 + kci * 32 + quad * 8];
            qf[mt][kci] = v;
        }
    }
    floatx4 o[4][4];
    #pragma unroll
    for (int mt = 0; mt < 4; ++mt)
        #pragma unroll
        for (int nt = 0; nt < 4; ++nt) o[mt][nt] = (floatx4){0.f, 0.f, 0.f, 0.f};

    const size_t mbase = ((size_t)b * THW + m * HW) * 256;
    const size_t vb = ((size_t)(b * 4 + m)) * 256 * VP;

    for (int kt = 0; kt < 16; ++kt) {
        const int k0 = kt * 64;
        int nv = HW - k0; if (nv > 64) nv = 64;
        __syncthreads();  // (A) prev tile's Vt/Ps reads done
        // stage M-tile [key][256ch], chunk swizzle ^(key&7)
        for (int it = 0; it < 8; ++it) {
            int v = it * 256 + tid;
            int key = v >> 5, ck = v & 31;
            ushort8 val = {0, 0, 0, 0, 0, 0, 0, 0};
            if (key < nv)
                val = *(const ushort8*)&Mbf[mbase + (size_t)(k0 + key) * 256 + ck * 8];
            *(ushort8*)&MV[key * 256 + ((ck ^ (key & 7)) << 3)] = val;
        }
        __syncthreads();  // (B)
        // scores: wave covers 16-key strip, 4 q-tiles
        floatx4 sc[4];
        #pragma unroll
        for (int mt = 0; mt < 4; ++mt) sc[mt] = (floatx4){0.f, 0.f, 0.f, 0.f};
        const int key = wv * 16 + l15;
        #pragma unroll
        for (int kci = 0; kci < 8; ++kci) {
            ushort8 bf = *(const ushort8*)&MV[key * 256 + (((kci * 4 + quad) ^ (key & 7)) << 3)];
            #pragma unroll
            for (int mt = 0; mt < 4; ++mt)
                sc[mt] = __builtin_amdgcn_mfma_f32_16x16x32_bf16(
                    __builtin_bit_cast(bf16x8, qf[mt][kci]),
                    __builtin_bit_cast(bf16x8, bf), sc[mt], 0, 0, 0);
        }
        #pragma unroll
        for (int mt = 0; mt < 4; ++mt)
            #pragma unroll
            for (int r = 0; r < 4; ++r)
                S[(mt * 16 + quad * 4 + r) * 67 + wv * 16 + l15] = sc[mt][r];
        __syncthreads();  // (C)
        if (tid < 128) {
            // softmax: 64 rows x 2 lanes, online update
            int row = tid >> 1, sub = tid & 1;
            float tmax = -1e30f;
            for (int t = 0; t < 32; ++t) {
                int j = sub + t * 2;
                if (j < nv) tmax = fmaxf(tmax, S[row * 67 + j]);
            }
            tmax = fmaxf(tmax, __shfl_xor(tmax, 1));
            float mo = m_s[row], mn = fmaxf(mo, tmax);
            float tsum = 0.f;
            for (int t = 0; t < 32; ++t) {
                int j = sub + t * 2;
                float p = 0.f;
                if (j < nv) p = __expf(S[row * 67 + j] - mn);
                tsum += p;
                Ps[row * 64 + (((j >> 3) ^ (row & 7)) << 3) + (j & 7)] = f2bf(p);
            }
            tsum += __shfl_xor(tsum, 1);
            if (sub == 0) {
                float al = __expf(mo - mn);
                alpha_s[row] = al;
                l_s[row] = l_s[row] * al + tsum;
                m_s[row] = mn;
            }
        } else {
            // stage V-tile [ch][64key] into MV (M-tile dead), swizzle ^(ch&7)
            int t2 = tid - 128;
            for (int it = 0; it < 32; ++it) {
                int u = it * 128 + t2;
                int ch = u >> 4, k = (u & 15) * 4;
                ushort4v val = {0, 0, 0, 0};
                if (k + 3 < nv) {
                    val = *(const ushort4v*)&Vbf[vb + (size_t)ch * VP + k0 + k];
                } else if (k < nv) {
                    for (int uu = 0; uu < 4; ++uu)
                        if (k + uu < nv) val[uu] = Vbf[vb + (size_t)ch * VP + k0 + k + uu];
                }
                *(ushort4v*)&MV[ch * 64 + (((k >> 3) ^ (ch & 7)) << 3) + (k & 7)] = val;
            }
        }
        __syncthreads();  // (D)
        // rescale O by alpha, then PV
        #pragma unroll
        for (int mt = 0; mt < 4; ++mt) {
            float al[4];
            #pragma unroll
            for (int r = 0; r < 4; ++r) al[r] = alpha_s[mt * 16 + quad * 4 + r];
            #pragma unroll
            for (int nt = 0; nt < 4; ++nt)
                #pragma unroll
                for (int r = 0; r < 4; ++r) o[mt][nt][r] *= al[r];
        }
        #pragma unroll
        for (int ks = 0; ks < 2; ++ks) {
            ushort8 af[4];
            #pragma unroll
            for (int mt = 0; mt < 4; ++mt) {
                int row = mt * 16 + l15;
                af[mt] = *(const ushort8*)&Ps[row * 64 + (((ks * 4 + quad) ^ (row & 7)) << 3)];
            }
            #pragma unroll
            for (int nt = 0; nt < 4; ++nt) {
                int ch = wv * 64 + nt * 16 + l15;
                ushort8 bv = *(const ushort8*)&MV[ch * 64 + (((ks * 4 + quad) ^ (ch & 7)) << 3)];
                #pragma unroll
                for (int mt = 0; mt < 4; ++mt)
                    o[mt][nt] = __builtin_amdgcn_mfma_f32_16x16x32_bf16(
                        __builtin_bit_cast(bf16x8, af[mt]),
                        __builtin_bit_cast(bf16x8, bv), o[mt][nt], 0, 0, 0);
            }
        }
    }
    // epilogue: normalize by l, store R fp32 channel-last
    #pragma unroll
    for (int mt = 0; mt < 4; ++mt) {
        float invl[4];
        #pragma unroll
        for (int r = 0; r < 4; ++r) invl[r] = 1.f / l_s[mt * 16 + quad * 4 + r];
        #pragma unroll
        for (int nt = 0; nt < 4; ++nt) {
            int ch = wv * 64 + nt * 16 + l15;
            #pragma unroll
            for (int r = 0; r < 4; ++r) {
                int q = q0 + mt * 16 + quad * 4 + r;
                if (q < THW)
                    R[(((size_t)(b * 4 + m)) * THW + q) * 256 + ch] = o[mt][nt][r] * invl[r];
            }
        }
    }
}

// ---------------- K4: Rmean + transpose to channel-first ----------------
__global__ __launch_bounds__(256) void k_rmean(const float* __restrict__ R,
                                               float* __restrict__ Rm) {
    __shared__ float tile[32][33];
    const int hw0 = blockIdx.x * 32, c0 = blockIdx.y * 32;
    const int bm = blockIdx.z, b = bm >> 2, m = bm & 3;
    const int tid = threadIdx.x;
    float acc[4] = {0.f, 0.f, 0.f, 0.f};
    #pragma unroll
    for (int tq = 0; tq < 4; ++tq) {
        const size_t base = ((size_t)(b * 4 + m) * THW + tq * HW) * 256;
        #pragma unroll
        for (int k = 0; k < 4; ++k) {
            int l = tid + k * 256;
            int hwl = l >> 5, cl = l & 31;
            if (hw0 + hwl < HW) acc[k] += R[base + (size_t)(hw0 + hwl) * 256 + c0 + cl];
        }
    }
    #pragma unroll
    for (int k = 0; k < 4; ++k) {
        int l = tid + k * 256;
        tile[l >> 5][l & 31] = acc[k] * 0.25f;
    }
    __syncthreads();
    #pragma unroll
    for (int k = 0; k < 4; ++k) {
        int l = tid + k * 256;
        int cl = l >> 5, hwl = l & 31;
        if (hw0 + hwl < HW)
            Rm[((size_t)b * 256 + c0 + cl) * THW + m * HW + hw0 + hwl] = tile[hwl][cl];
    }
}

// ---------------- K5: compare branch convs (pre-BN) ----------------
__global__ __launch_bounds__(256) void k_compare(
    const float* __restrict__ R, const float* __restrict__ V,
    const float* __restrict__ Wcat, const float* __restrict__ Wsub,
    const float* __restrict__ Wmul, float* __restrict__ Pc) {
    __shared__ float Rt[31][257];
    __shared__ float Vt[31][257];
    const int hw0 = blockIdx.x * 31, s = blockIdx.y, b = blockIdx.z;
    const int m = s >> 2, tq = s & 3;
    const int tid = threadIdx.x;
    const size_t rbase = ((size_t)(b * 4 + m) * THW + tq * HW + hw0) * 256;
    const size_t vbase = ((size_t)b * THW + m * HW + hw0) * 256;
    for (int l = tid; l < 31 * 64; l += 256) {
        int row = l >> 6, c4 = (l & 63) * 4;
        float4 rv = *(const float4*)&R[rbase + (size_t)row * 256 + c4];
        float4 vv = *(const float4*)&V[vbase + (size_t)row * 256 + c4];
        Rt[row][c4 + 0] = rv.x; Rt[row][c4 + 1] = rv.y; Rt[row][c4 + 2] = rv.z; Rt[row][c4 + 3] = rv.w;
        Vt[row][c4 + 0] = vv.x; Vt[row][c4 + 1] = vv.y; Vt[row][c4 + 2] = vv.z; Vt[row][c4 + 3] = vv.w;
    }
    __syncthreads();
    const int px = tid & 31, g = tid >> 5;
    if (px < 31) {
        for (int kk = 0; kk < 16; ++kk) {
            int ci = g + (kk << 3);
            if (ci >= NCMP) break;
            float acc = 0.f;
            if (ci < 42) {
                const float* wr = Wcat + (size_t)ci * 512;
                #pragma unroll 4
                for (int k = 0; k < 256; ++k)
                    acc += wr[k] * Rt[px][k] + wr[256 + k] * Vt[px][k];
            } else if (ci < 84) {
                const float* wr = Wsub + (size_t)(ci - 42) * 256;
                #pragma unroll 4
                for (int k = 0; k < 256; ++k) acc += wr[k] * (Rt[px][k] - Vt[px][k]);
            } else {
                const float* wr = Wmul + (size_t)(ci - 84) * 256;
                #pragma unroll 4
                for (int k = 0; k < 256; ++k) acc += wr[k] * (Rt[px][k] * Vt[px][k]);
            }
            Pc[((size_t)(b * NCMP + ci) * 16 + s) * HW + hw0 + px] = acc;
        }
    }
}

// ---------------- K6: BN stats for compare ----------------
__global__ __launch_bounds__(256) void k_stats_cmp(
    const float* __restrict__ Pc, const float* __restrict__ g_cat,
    const float* __restrict__ b_cat, const float* __restrict__ g_sub,
    const float* __restrict__ b_sub, const float* __restrict__ g_mul,
    const float* __restrict__ b_mul, float* __restrict__ bnc) {
    const int c = blockIdx.x, tid = threadIdx.x;
    float s = 0.f, q = 0.f;
    for (int i = tid; i < 4 * 16 * HW; i += 256) {
        int bb = i / (16 * HW), r = i - bb * (16 * HW);
        float v = Pc[(size_t)(bb * NCMP + c) * (16 * HW) + r];
        s += v; q += v * v;
    }
    __shared__ float rs[256], rq[256];
    rs[tid] = s; rq[tid] = q;
    __syncthreads();
    for (int off = 128; off > 0; off >>= 1) {
        if (tid < off) { rs[tid] += rs[tid + off]; rq[tid] += rq[tid + off]; }
        __syncthreads();
    }
    if (tid == 0) {
        const float n = 4.f * 16.f * HW;
        float mean = rs[0] / n;
        float var = rq[0] / n - mean * mean;
        float g, bt;
        if (c < 42)       { g = g_cat[c];      bt = b_cat[c]; }
        else if (c < 84)  { g = g_sub[c - 42]; bt = b_sub[c - 42]; }
        else              { g = g_mul[c - 84]; bt = b_mul[c - 84]; }
        float sc = g * rsqrtf(var + BN_EPS);
        bnc[c] = sc;
        bnc[NCMP + c] = bt - mean * sc;
    }
}

// ---------------- K7: aggregate GEMM ----------------
__global__ __launch_bounds__(256) void k_agg(
    const float* __restrict__ Wagg, const float* __restrict__ Rm,
    const float* __restrict__ Vcf, const float* __restrict__ Pc,
    const float* __restrict__ bnc, float* __restrict__ Z) {
    __shared__ float Wt[16][64];
    __shared__ float Yt[16][64];
    const int p0 = blockIdx.x * 64, oc0 = blockIdx.y * 64, b = blockIdx.z;
    const int tx = threadIdx.x, ty = threadIdx.y;
    const int tid = ty * 16 + tx;
    float acc[4][4] = {{0.f}};
    for (int kc = 0; kc < AGGK; kc += 16) {
        __syncthreads();
        for (int l = tid; l < 1024; l += 256) {
            int kk = l & 15, j = l >> 4;
            int ic = kc + kk;
            Wt[kk][j] = (ic < AGGK) ? Wagg[(size_t)(oc0 + j) * AGGK + ic] : 0.f;
        }
        for (int l = tid; l < 1024; l += 256) {
            int pp = l & 63, kk = l >> 6;
            int ic = kc + kk, p = p0 + pp;
            float v = 0.f;
            if (p < THW && ic < AGGK) {
                if (ic < 256) v = Rm[((size_t)b * 256 + ic) * THW + p];
                else if (ic < 512) v = Vcf[((size_t)b * 256 + (ic - 256)) * THW + p];
                else {
                    int j2 = ic - 512;
                    int co = j2 >> 2, mm = j2 & 3;
                    int tq = p / HW, hw = p - tq * HW;
                    float pv = Pc[((size_t)(b * NCMP + co) * 16 + (mm * 4 + tq)) * HW + hw];
                    v = fmaxf(fmaf(pv, bnc[co], bnc[NCMP + co]), 0.f);
                }
            }
            Yt[kk][pp] = v;
        }
        __syncthreads();
        #pragma unroll
        for (int kk = 0; kk < 16; ++kk) {
            float a[4], c[4];
            *(float4*)a = *(const float4*)&Wt[kk][ty * 4];
            *(float4*)c = *(const float4*)&Yt[kk][tx * 4];
            #pragma unroll
            for (int i = 0; i < 4; ++i)
                #pragma unroll
                for (int j = 0; j < 4; ++j) acc[i][j] = fmaf(a[i], c[j], acc[i][j]);
        }
    }
    const int oc = oc0 + ty * 4;
    const int pb = p0 + tx * 4;
    if (pb < THW) {
        #pragma unroll
        for (int i = 0; i < 4; ++i) {
            float4 v = make_float4(acc[i][0], acc[i][1], acc[i][2], acc[i][3]);
            *(float4*)&Z[((size_t)b * Cch + oc + i) * THW + pb] = v;
        }
    }
}

// ---------------- K8: BN stats for aggregate ----------------
__global__ __launch_bounds__(256) void k_stats_agg(
    const float* __restrict__ Z, const float* __restrict__ g_agg,
    const float* __restrict__ b_agg, float* __restrict__ bna) {
    const int c = blockIdx.x, tid = threadIdx.x;
    float s = 0.f, q = 0.f;
    for (int i = tid; i < 4 * THW; i += 256) {
        int bb = i / THW, p = i - bb * THW;
        float v = Z[((size_t)bb * Cch + c) * THW + p];
        s += v; q += v * v;
    }
    __shared__ float rs[256], rq[256];
    rs[tid] = s; rq[tid] = q;
    __syncthreads();
    for (int off = 128; off > 0; off >>= 1) {
        if (tid < off) { rs[tid] += rs[tid + off]; rq[tid] += rq[tid + off]; }
        __syncthreads();
    }
    if (tid == 0) {
        const float n = 4.f * THW;
        float mean = rs[0] / n;
        float var = rq[0] / n - mean * mean;
        float sc = g_agg[c] * rsqrtf(var + BN_EPS);
        bna[c] = sc;
        bna[Cch + c] = b_agg[c] - mean * sc;
    }
}

// ---------------- K9: out = relu(xp + BN(Z)) ----------------
__global__ __launch_bounds__(256) void k_final(const float* __restrict__ xp,
                                               const float* __restrict__ Z,
                                               const float* __restrict__ bna,
                                               float* __restrict__ out) {
    int idx = blockIdx.x * 256 + threadIdx.x;
    if (idx >= NPIX) return;
    int c = (idx / THW) & 511;
    out[idx] = fmaxf(fmaf(Z[idx], bna[c], bna[Cch + c]) + xp[idx], 0.f);
}

extern "C" void kernel_launch(void* const* d_in, const int* in_sizes, int n_in,
                              void* d_out, int out_size, void* d_ws, size_t ws_size,
                              hipStream_t stream) {
    const float* x     = (const float*)d_in[0];
    const float* Wq    = (const float*)d_in[1];
    const float* Wm    = (const float*)d_in[2];
    const float* Wv    = (const float*)d_in[3];
    const float* Wcat  = (const float*)d_in[4];
    const float* Wsub  = (const float*)d_in[5];
    const float* Wmul  = (const float*)d_in[6];
    const float* g_cat = (const float*)d_in[7];
    const float* b_cat = (const float*)d_in[8];
    const float* g_sub = (const float*)d_in[9];
    const float* b_sub = (const float*)d_in[10];
    const float* g_mul = (const float*)d_in[11];
    const float* b_mul = (const float*)d_in[12];
    const float* Wagg  = (const float*)d_in[13];
    const float* g_agg = (const float*)d_in[14];
    const float* b_agg = (const float*)d_in[15];
    float* out = (float*)d_out;
    float* ws  = (float*)d_ws;

    // workspace layout (floats); total 45,160,960 floats = 180.6 MB
    float* xp  = ws;                 // 7,872,512
    float* Vcl = xp  + 7872512;      // 3,936,256 fp32 channel-last (compare)
    float* Vcf = Vcl + 3936256;      // 3,936,256 fp32 channel-first (aggregate)
    float* R   = Vcf + 3936256;      // 15,745,024 (b,m,q,c)
    float* Pc  = R   + 15745024;     // 7,750,656
    float* bnc = Pc  + 7750656;      // 512
    float* bna = bnc + 512;          // 1024
    unsigned short* Qbf = (unsigned short*)(bna + 1024);  // 3,936,256 ushorts
    unsigned short* Mbf = Qbf + 3936256;                  // 3,936,256
    unsigned short* Vbf = Mbf + 3936256;                  // 4*4*256*968 = 3,964,928
    float* Rm = (float*)Qbf;  // alias: Qbf+Mbf dead after attention (3,936,256 floats)
    float* Z  = R;            // alias: R dead after rmean+compare

    k_pool<<<dim3((NPIX + 255) / 256), dim3(256), 0, stream>>>(x, xp);
    k_qmv<<<dim3(61, 12, Bb), dim3(16, 16), 0, stream>>>(xp, Wq, Wm, Wv, Qbf, Mbf,
                                                         Vcl, Vcf, Vbf);
    k_attn_mfma<<<dim3(61, 4, Bb), dim3(256), 0, stream>>>(Qbf, Mbf, Vbf, R);
    k_rmean<<<dim3(31, 8, 16), dim3(256), 0, stream>>>(R, Rm);
    k_compare<<<dim3(31, 16, Bb), dim3(256), 0, stream>>>(R, Vcl, Wcat, Wsub, Wmul, Pc);
    k_stats_cmp<<<dim3(NCMP), dim3(256), 0, stream>>>(Pc, g_cat, b_cat, g_sub, b_sub,
                                                      g_mul, b_mul, bnc);
    k_agg<<<dim3(61, 8, Bb), dim3(16, 16), 0, stream>>>(Wagg, Rm, Vcf, Pc, bnc, Z);
    k_stats_agg<<<dim3(Cch), dim3(256), 0, stream>>>(Z, g_agg, b_agg, bna);
    k_final<<<dim3((NPIX + 255) / 256), dim3(256), 0, stream>>>(xp, Z, bna, out);
}

// Round 3
// 1892.285 us; speedup vs baseline: 5.1136x; 1.1933x over previous
//
#include <hip/hip_runtime.h>
#include <math.h>

// Problem dims
constexpr int Bb   = 4;
constexpr int Cch  = 512;
constexpr int HW   = 961;      // 31*31
constexpr int THW  = 3844;     // 4*961
constexpr int NCMP = 126;      // 3*42 compare channels
constexpr int AGGK = 1016;
constexpr int NPIX = Bb * Cch * THW;  // 7,872,512
constexpr int Hp = 31, Wp = 31, H0c = 63, W0c = 63;
constexpr int VP = 1024;       // padded keys/frame for Vbf: staging never needs tail guards
#define BN_EPS 1e-5f

typedef __attribute__((ext_vector_type(4))) float floatx4;
typedef __attribute__((ext_vector_type(8))) __bf16 bf16x8;
typedef __attribute__((ext_vector_type(8))) unsigned short ushort8;
typedef __attribute__((ext_vector_type(4))) unsigned short ushort4v;

static __device__ __forceinline__ unsigned short f2bf(float x) {
    unsigned int u = __builtin_bit_cast(unsigned int, x);
    u += 0x7fff + ((u >> 16) & 1);   // RNE
    return (unsigned short)(u >> 16);
}

// ---------------- K1: maxpool (1,3,3)/(1,2,2) ----------------
__global__ __launch_bounds__(256) void k_pool(const float* __restrict__ x,
                                              float* __restrict__ xp) {
    int idx = blockIdx.x * 256 + threadIdx.x;
    if (idx >= NPIX) return;
    int w = idx % Wp;
    int h = (idx / Wp) % Hp;
    int bct = idx / HW;
    const float* src = x + (size_t)bct * (H0c * W0c) + (2 * h) * W0c + 2 * w;
    float m = -INFINITY;
    #pragma unroll
    for (int i = 0; i < 3; ++i) {
        m = fmaxf(m, src[i * W0c + 0]);
        m = fmaxf(m, src[i * W0c + 1]);
        m = fmaxf(m, src[i * W0c + 2]);
    }
    xp[idx] = m;
}

// ---------------- K2: Q/M/V projections (tiled fp32 GEMM, bf16 side outputs) ----
__global__ __launch_bounds__(256) void k_qmv(
    const float* __restrict__ xp, const float* __restrict__ Wq,
    const float* __restrict__ Wm, const float* __restrict__ Wv,
    unsigned short* __restrict__ Qbf, unsigned short* __restrict__ Mbf,
    float* __restrict__ Vcl, float* __restrict__ Vcf,
    unsigned short* __restrict__ Vbf) {
    __shared__ float Wt[16][64];
    __shared__ float Xt[16][64];
    const int p0  = blockIdx.x * 64;
    const int oc0 = blockIdx.y * 64;
    const int b   = blockIdx.z;
    const int sel = oc0 >> 8;          // 0:Q 1:M 2:V
    const int ocr = oc0 & 255;
    const float* Wbase = (sel == 0) ? Wq : (sel == 1) ? Wm : Wv;
    const int tx = threadIdx.x, ty = threadIdx.y;
    const int tid = ty * 16 + tx;
    float acc[4][4] = {{0.f}};
    for (int kc = 0; kc < 512; kc += 16) {
        __syncthreads();
        for (int l = tid; l < 1024; l += 256) {
            int kk = l & 15, j = l >> 4;
            Wt[kk][j] = Wbase[(size_t)(ocr + j) * 512 + kc + kk];
        }
        for (int l = tid; l < 1024; l += 256) {
            int pp = l & 63, kk = l >> 6;
            int p = p0 + pp;
            Xt[kk][pp] = (p < THW) ? xp[(size_t)(b * Cch + kc + kk) * THW + p] : 0.f;
        }
        __syncthreads();
        #pragma unroll
        for (int kk = 0; kk < 16; ++kk) {
            float a[4], c[4];
            *(float4*)a = *(const float4*)&Wt[kk][ty * 4];
            *(float4*)c = *(const float4*)&Xt[kk][tx * 4];
            #pragma unroll
            for (int i = 0; i < 4; ++i)
                #pragma unroll
                for (int j = 0; j < 4; ++j) acc[i][j] = fmaf(a[i], c[j], acc[i][j]);
        }
    }
    const int ocl = ocr + ty * 4;
    if (sel < 2) {
        unsigned short* outbf = (sel == 0) ? Qbf : Mbf;
        const float scale = (sel == 0) ? 0.0625f : 1.0f;
        #pragma unroll
        for (int j = 0; j < 4; ++j) {
            int p = p0 + tx * 4 + j;
            if (p < THW) {
                ushort4v v;
                #pragma unroll
                for (int i = 0; i < 4; ++i) v[i] = f2bf(acc[i][j] * scale);
                *(ushort4v*)&outbf[((size_t)b * THW + p) * 256 + ocl] = v;
            }
        }
    } else {
        #pragma unroll
        for (int j = 0; j < 4; ++j) {
            int p = p0 + tx * 4 + j;
            if (p < THW) {
                float4 v = make_float4(acc[0][j], acc[1][j], acc[2][j], acc[3][j]);
                *(float4*)&Vcl[((size_t)b * THW + p) * 256 + ocl] = v;
            }
        }
        int pb = p0 + tx * 4;
        if (pb < THW) {
            #pragma unroll
            for (int i = 0; i < 4; ++i) {
                float4 v = make_float4(acc[i][0], acc[i][1], acc[i][2], acc[i][3]);
                *(float4*)&Vcf[((size_t)b * 256 + ocl + i) * THW + pb] = v;
            }
            #pragma unroll
            for (int j = 0; j < 4; ++j) {
                int p = pb + j;
                int mm = p / HW, key = p - mm * HW;
                #pragma unroll
                for (int i = 0; i < 4; ++i)
                    Vbf[(((size_t)(b * 4 + mm)) * 256 + ocl + i) * VP + key] =
                        f2bf(acc[i][j]);
            }
        }
    }
}

// ---------------- K3: flash attention, bf16 MFMA, register softmax ----------------
// grid (16, 61): x = b*4+m (same-frame blocks land on same XCD under id%8), y = q-tile
__global__ __launch_bounds__(256, 2) void k_attn_mfma(
    const unsigned short* __restrict__ Qbf, const unsigned short* __restrict__ Mbf,
    const unsigned short* __restrict__ Vbf, float* __restrict__ R) {
    // LDS: MV 32KB + Ps 8KB + stats 2KB + alpha 256B ~= 42.5 KB
    __shared__ unsigned short MV[16384] __attribute__((aligned(16)));  // M[64k][256c] | V[256c][64k], XOR swizzle
    __shared__ unsigned short Ps[4096] __attribute__((aligned(16)));   // P[64q][64k] swizzle
    __shared__ float stat_mx[4][64];   // per-wave strip max, per query
    __shared__ float stat_sm[4][64];   // per-wave strip sum
    __shared__ float alpha_s[64];

    const int bm = blockIdx.x;
    const int b = bm >> 2, m = bm & 3;
    const int q0 = blockIdx.y * 64;
    const int tid = threadIdx.x;
    const int wv = tid >> 6, lane = tid & 63;
    const int l15 = lane & 15, quad = lane >> 4;

    // Q fragments in registers: query = mt*16 + l15, k = kci*32 + quad*8 + j
    ushort8 qf[4][8];
    #pragma unroll
    for (int mt = 0; mt < 4; ++mt) {
        int q = q0 + mt * 16 + l15;
        #pragma unroll
        for (int kci = 0; kci < 8; ++kci) {
            ushort8 v = {0, 0, 0, 0, 0, 0, 0, 0};
            if (q < THW)
                v = *(const ushort8*)&Qbf[((size_t)b * THW + q) * 256 + kci * 32 + quad * 8];
            qf[mt][kci] = v;
        }
    }
    floatx4 o[4][4];
    #pragma unroll
    for (int mt = 0; mt < 4; ++mt)
        #pragma unroll
        for (int nt = 0; nt < 4; ++nt) o[mt][nt] = (floatx4){0.f, 0.f, 0.f, 0.f};
    float m_run[4], l_run[4];
    #pragma unroll
    for (int mt = 0; mt < 4; ++mt) { m_run[mt] = -1e30f; l_run[mt] = 0.f; }

    const size_t mbase = ((size_t)b * THW + m * HW) * 256;
    const size_t vb = (size_t)bm * 256 * VP;

    for (int kt = 0; kt < 16; ++kt) {
        const int k0 = kt * 64;
        int nv = HW - k0; if (nv > 64) nv = 64;
        __syncthreads();  // A: prev tile's Ps/V reads done
        // stage M-tile [key][256ch], chunk swizzle ^(key&7)
        #pragma unroll
        for (int it = 0; it < 8; ++it) {
            int v = it * 256 + tid;
            int key = v >> 5, ck = v & 31;
            ushort8 val = {0, 0, 0, 0, 0, 0, 0, 0};
            if (key < nv)
                val = *(const ushort8*)&Mbf[mbase + (size_t)(k0 + key) * 256 + ck * 8];
            *(ushort8*)&MV[key * 256 + ((ck ^ (key & 7)) << 3)] = val;
        }
        __syncthreads();  // B
        // QK^T with swapped operands: C[row = key_local = quad*4+r][col = query = mt*16+l15]
        floatx4 sc[4];
        #pragma unroll
        for (int mt = 0; mt < 4; ++mt) sc[mt] = (floatx4){0.f, 0.f, 0.f, 0.f};
        const int mkey = wv * 16 + l15;
        #pragma unroll
        for (int kci = 0; kci < 8; ++kci) {
            ushort8 mf = *(const ushort8*)&MV[mkey * 256 + (((kci * 4 + quad) ^ (mkey & 7)) << 3)];
            #pragma unroll
            for (int mt = 0; mt < 4; ++mt)
                sc[mt] = __builtin_amdgcn_mfma_f32_16x16x32_bf16(
                    __builtin_bit_cast(bf16x8, mf),
                    __builtin_bit_cast(bf16x8, qf[mt][kci]), sc[mt], 0, 0, 0);
        }
        // mask OOB keys (this lane's keys: wv*16 + quad*4 + r)
        #pragma unroll
        for (int r = 0; r < 4; ++r) {
            if (wv * 16 + quad * 4 + r >= nv) {
                #pragma unroll
                for (int mt = 0; mt < 4; ++mt) sc[mt][r] = -1e30f;
            }
        }
        // strip max/sum per query: 3 reg-max + 2 shuffles (quad bits = lane bits 4,5)
        float mx[4], sm[4];
        #pragma unroll
        for (int mt = 0; mt < 4; ++mt) {
            float v = fmaxf(fmaxf(sc[mt][0], sc[mt][1]), fmaxf(sc[mt][2], sc[mt][3]));
            v = fmaxf(v, __shfl_xor(v, 16));
            v = fmaxf(v, __shfl_xor(v, 32));
            mx[mt] = v;
        }
        #pragma unroll
        for (int mt = 0; mt < 4; ++mt) {
            float s = 0.f;
            #pragma unroll
            for (int r = 0; r < 4; ++r) {
                bool oob = (wv * 16 + quad * 4 + r) >= nv;
                float p = oob ? 0.f : __expf(sc[mt][r] - mx[mt]);
                sc[mt][r] = p;   // reuse as p_local
                s += p;
            }
            s += __shfl_xor(s, 16);
            s += __shfl_xor(s, 32);
            sm[mt] = s;
        }
        if (quad == 0) {
            #pragma unroll
            for (int mt = 0; mt < 4; ++mt) {
                stat_mx[wv][mt * 16 + l15] = mx[mt];
                stat_sm[wv][mt * 16 + l15] = sm[mt];
            }
        }
        __syncthreads();  // C: stats visible; all M-reads done
        // combine strips, online update (redundant across waves; all in regs)
        float fown[4];
        #pragma unroll
        for (int mt = 0; mt < 4; ++mt) {
            int qrow = mt * 16 + l15;
            float m0 = stat_mx[0][qrow], m1 = stat_mx[1][qrow];
            float m2 = stat_mx[2][qrow], m3 = stat_mx[3][qrow];
            float gmax = fmaxf(fmaxf(m0, m1), fmaxf(m2, m3));
            float mn = fmaxf(m_run[mt], gmax);
            float al = __expf(m_run[mt] - mn);
            float e0 = __expf(m0 - mn), e1 = __expf(m1 - mn);
            float e2 = __expf(m2 - mn), e3 = __expf(m3 - mn);
            l_run[mt] = l_run[mt] * al + stat_sm[0][qrow] * e0 + stat_sm[1][qrow] * e1
                      + stat_sm[2][qrow] * e2 + stat_sm[3][qrow] * e3;
            m_run[mt] = mn;
            fown[mt] = (wv == 0) ? e0 : (wv == 1) ? e1 : (wv == 2) ? e2 : e3;
            if (wv == 0 && quad == 0) alpha_s[qrow] = al;
        }
        // write P_adj bf16: P[key = wv*16+quad*4+r][query = mt*16+l15] -> Ps[query][key]
        #pragma unroll
        for (int mt = 0; mt < 4; ++mt) {
            int qrow = mt * 16 + l15;
            int base = qrow * 64;
            #pragma unroll
            for (int r = 0; r < 4; ++r) {
                int key = wv * 16 + quad * 4 + r;
                Ps[base + (((key >> 3) ^ (qrow & 7)) << 3) + (key & 7)] =
                    f2bf(sc[mt][r] * fown[mt]);
            }
        }
        // stage V-tile [ch][64key] into MV (M region dead), swizzle ^(ch&7)
        #pragma unroll
        for (int it = 0; it < 8; ++it) {
            int u = it * 256 + tid;
            int ch = u >> 3, k8 = (u & 7) << 3;
            ushort8 val = *(const ushort8*)&Vbf[vb + (size_t)ch * VP + k0 + k8];
            *(ushort8*)&MV[ch * 64 + (((k8 >> 3) ^ (ch & 7)) << 3)] = val;
        }
        __syncthreads();  // D
        // rescale O by alpha (o rows = mt*16 + quad*4 + r)
        #pragma unroll
        for (int mt = 0; mt < 4; ++mt) {
            float al[4];
            #pragma unroll
            for (int r = 0; r < 4; ++r) al[r] = alpha_s[mt * 16 + quad * 4 + r];
            #pragma unroll
            for (int nt = 0; nt < 4; ++nt)
                #pragma unroll
                for (int r = 0; r < 4; ++r) o[mt][nt][r] *= al[r];
        }
        // PV: A = P (query-major), B = V — same verified layout as before
        #pragma unroll
        for (int ks = 0; ks < 2; ++ks) {
            ushort8 af[4];
            #pragma unroll
            for (int mt = 0; mt < 4; ++mt) {
                int row = mt * 16 + l15;
                af[mt] = *(const ushort8*)&Ps[row * 64 + (((ks * 4 + quad) ^ (row & 7)) << 3)];
            }
            #pragma unroll
            for (int nt = 0; nt < 4; ++nt) {
                int ch = wv * 64 + nt * 16 + l15;
                ushort8 bv = *(const ushort8*)&MV[ch * 64 + (((ks * 4 + quad) ^ (ch & 7)) << 3)];
                #pragma unroll
                for (int mt = 0; mt < 4; ++mt)
                    o[mt][nt] = __builtin_amdgcn_mfma_f32_16x16x32_bf16(
                        __builtin_bit_cast(bf16x8, af[mt]),
                        __builtin_bit_cast(bf16x8, bv), o[mt][nt], 0, 0, 0);
            }
        }
    }
    // epilogue: move l across lane mappings via LDS, then store R
    if (wv == 0 && quad == 0) {
        #pragma unroll
        for (int mt = 0; mt < 4; ++mt) stat_mx[0][mt * 16 + l15] = l_run[mt];
    }
    __syncthreads();
    #pragma unroll
    for (int mt = 0; mt < 4; ++mt) {
        float invl[4];
        #pragma unroll
        for (int r = 0; r < 4; ++r) invl[r] = 1.f / stat_mx[0][mt * 16 + quad * 4 + r];
        #pragma unroll
        for (int nt = 0; nt < 4; ++nt) {
            int ch = wv * 64 + nt * 16 + l15;
            #pragma unroll
            for (int r = 0; r < 4; ++r) {
                int q = q0 + mt * 16 + quad * 4 + r;
                if (q < THW)
                    R[(((size_t)bm) * THW + q) * 256 + ch] = o[mt][nt][r] * invl[r];
            }
        }
    }
}

// ---------------- K4: Rmean + transpose to channel-first ----------------
__global__ __launch_bounds__(256) void k_rmean(const float* __restrict__ R,
                                               float* __restrict__ Rm) {
    __shared__ float tile[32][33];
    const int hw0 = blockIdx.x * 32, c0 = blockIdx.y * 32;
    const int bm = blockIdx.z, b = bm >> 2, m = bm & 3;
    const int tid = threadIdx.x;
    float acc[4] = {0.f, 0.f, 0.f, 0.f};
    #pragma unroll
    for (int tq = 0; tq < 4; ++tq) {
        const size_t base = ((size_t)(b * 4 + m) * THW + tq * HW) * 256;
        #pragma unroll
        for (int k = 0; k < 4; ++k) {
            int l = tid + k * 256;
            int hwl = l >> 5, cl = l & 31;
            if (hw0 + hwl < HW) acc[k] += R[base + (size_t)(hw0 + hwl) * 256 + c0 + cl];
        }
    }
    #pragma unroll
    for (int k = 0; k < 4; ++k) {
        int l = tid + k * 256;
        tile[l >> 5][l & 31] = acc[k] * 0.25f;
    }
    __syncthreads();
    #pragma unroll
    for (int k = 0; k < 4; ++k) {
        int l = tid + k * 256;
        int cl = l >> 5, hwl = l & 31;
        if (hw0 + hwl < HW)
            Rm[((size_t)b * 256 + c0 + cl) * THW + m * HW + hw0 + hwl] = tile[hwl][cl];
    }
}

// ---------------- K5: compare branch convs (pre-BN) ----------------
__global__ __launch_bounds__(256) void k_compare(
    const float* __restrict__ R, const float* __restrict__ V,
    const float* __restrict__ Wcat, const float* __restrict__ Wsub,
    const float* __restrict__ Wmul, float* __restrict__ Pc) {
    __shared__ float Rt[31][257];
    __shared__ float Vt[31][257];
    const int hw0 = blockIdx.x * 31, s = blockIdx.y, b = blockIdx.z;
    const int m = s >> 2, tq = s & 3;
    const int tid = threadIdx.x;
    const size_t rbase = ((size_t)(b * 4 + m) * THW + tq * HW + hw0) * 256;
    const size_t vbase = ((size_t)b * THW + m * HW + hw0) * 256;
    for (int l = tid; l < 31 * 64; l += 256) {
        int row = l >> 6, c4 = (l & 63) * 4;
        float4 rv = *(const float4*)&R[rbase + (size_t)row * 256 + c4];
        float4 vv = *(const float4*)&V[vbase + (size_t)row * 256 + c4];
        Rt[row][c4 + 0] = rv.x; Rt[row][c4 + 1] = rv.y; Rt[row][c4 + 2] = rv.z; Rt[row][c4 + 3] = rv.w;
        Vt[row][c4 + 0] = vv.x; Vt[row][c4 + 1] = vv.y; Vt[row][c4 + 2] = vv.z; Vt[row][c4 + 3] = vv.w;
    }
    __syncthreads();
    const int px = tid & 31, g = tid >> 5;
    if (px < 31) {
        for (int kk = 0; kk < 16; ++kk) {
            int ci = g + (kk << 3);
            if (ci >= NCMP) break;
            float acc = 0.f;
            if (ci < 42) {
                const float* wr = Wcat + (size_t)ci * 512;
                #pragma unroll 4
                for (int k = 0; k < 256; ++k)
                    acc += wr[k] * Rt[px][k] + wr[256 + k] * Vt[px][k];
            } else if (ci < 84) {
                const float* wr = Wsub + (size_t)(ci - 42) * 256;
                #pragma unroll 4
                for (int k = 0; k < 256; ++k) acc += wr[k] * (Rt[px][k] - Vt[px][k]);
            } else {
                const float* wr = Wmul + (size_t)(ci - 84) * 256;
                #pragma unroll 4
                for (int k = 0; k < 256; ++k) acc += wr[k] * (Rt[px][k] * Vt[px][k]);
            }
            Pc[((size_t)(b * NCMP + ci) * 16 + s) * HW + hw0 + px] = acc;
        }
    }
}

// ---------------- K6: BN stats for compare ----------------
__global__ __launch_bounds__(256) void k_stats_cmp(
    const float* __restrict__ Pc, const float* __restrict__ g_cat,
    const float* __restrict__ b_cat, const float* __restrict__ g_sub,
    const float* __restrict__ b_sub, const float* __restrict__ g_mul,
    const float* __restrict__ b_mul, float* __restrict__ bnc) {
    const int c = blockIdx.x, tid = threadIdx.x;
    float s = 0.f, q = 0.f;
    for (int i = tid; i < 4 * 16 * HW; i += 256) {
        int bb = i / (16 * HW), r = i - bb * (16 * HW);
        float v = Pc[(size_t)(bb * NCMP + c) * (16 * HW) + r];
        s += v; q += v * v;
    }
    __shared__ float rs[256], rq[256];
    rs[tid] = s; rq[tid] = q;
    __syncthreads();
    for (int off = 128; off > 0; off >>= 1) {
        if (tid < off) { rs[tid] += rs[tid + off]; rq[tid] += rq[tid + off]; }
        __syncthreads();
    }
    if (tid == 0) {
        const float n = 4.f * 16.f * HW;
        float mean = rs[0] / n;
        float var = rq[0] / n - mean * mean;
        float g, bt;
        if (c < 42)       { g = g_cat[c];      bt = b_cat[c]; }
        else if (c < 84)  { g = g_sub[c - 42]; bt = b_sub[c - 42]; }
        else              { g = g_mul[c - 84]; bt = b_mul[c - 84]; }
        float sc = g * rsqrtf(var + BN_EPS);
        bnc[c] = sc;
        bnc[NCMP + c] = bt - mean * sc;
    }
}

// ---------------- K7: aggregate GEMM ----------------
__global__ __launch_bounds__(256) void k_agg(
    const float* __restrict__ Wagg, const float* __restrict__ Rm,
    const float* __restrict__ Vcf, const float* __restrict__ Pc,
    const float* __restrict__ bnc, float* __restrict__ Z) {
    __shared__ float Wt[16][64];
    __shared__ float Yt[16][64];
    const int p0 = blockIdx.x * 64, oc0 = blockIdx.y * 64, b = blockIdx.z;
    const int tx = threadIdx.x, ty = threadIdx.y;
    const int tid = ty * 16 + tx;
    float acc[4][4] = {{0.f}};
    for (int kc = 0; kc < AGGK; kc += 16) {
        __syncthreads();
        for (int l = tid; l < 1024; l += 256) {
            int kk = l & 15, j = l >> 4;
            int ic = kc + kk;
            Wt[kk][j] = (ic < AGGK) ? Wagg[(size_t)(oc0 + j) * AGGK + ic] : 0.f;
        }
        for (int l = tid; l < 1024; l += 256) {
            int pp = l & 63, kk = l >> 6;
            int ic = kc + kk, p = p0 + pp;
            float v = 0.f;
            if (p < THW && ic < AGGK) {
                if (ic < 256) v = Rm[((size_t)b * 256 + ic) * THW + p];
                else if (ic < 512) v = Vcf[((size_t)b * 256 + (ic - 256)) * THW + p];
                else {
                    int j2 = ic - 512;
                    int co = j2 >> 2, mm = j2 & 3;
                    int tq = p / HW, hw = p - tq * HW;
                    float pv = Pc[((size_t)(b * NCMP + co) * 16 + (mm * 4 + tq)) * HW + hw];
                    v = fmaxf(fmaf(pv, bnc[co], bnc[NCMP + co]), 0.f);
                }
            }
            Yt[kk][pp] = v;
        }
        __syncthreads();
        #pragma unroll
        for (int kk = 0; kk < 16; ++kk) {
            float a[4], c[4];
            *(float4*)a = *(const float4*)&Wt[kk][ty * 4];
            *(float4*)c = *(const float4*)&Yt[kk][tx * 4];
            #pragma unroll
            for (int i = 0; i < 4; ++i)
                #pragma unroll
                for (int j = 0; j < 4; ++j) acc[i][j] = fmaf(a[i], c[j], acc[i][j]);
        }
    }
    const int oc = oc0 + ty * 4;
    const int pb = p0 + tx * 4;
    if (pb < THW) {
        #pragma unroll
        for (int i = 0; i < 4; ++i) {
            float4 v = make_float4(acc[i][0], acc[i][1], acc[i][2], acc[i][3]);
            *(float4*)&Z[((size_t)b * Cch + oc + i) * THW + pb] = v;
        }
    }
}

// ---------------- K8: BN stats for aggregate ----------------
__global__ __launch_bounds__(256) void k_stats_agg(
    const float* __restrict__ Z, const float* __restrict__ g_agg,
    const float* __restrict__ b_agg, float* __restrict__ bna) {
    const int c = blockIdx.x, tid = threadIdx.x;
    float s = 0.f, q = 0.f;
    for (int i = tid; i < 4 * THW; i += 256) {
        int bb = i / THW, p = i - bb * THW;
        float v = Z[((size_t)bb * Cch + c) * THW + p];
        s += v; q += v * v;
    }
    __shared__ float rs[256], rq[256];
    rs[tid] = s; rq[tid] = q;
    __syncthreads();
    for (int off = 128; off > 0; off >>= 1) {
        if (tid < off) { rs[tid] += rs[tid + off]; rq[tid] += rq[tid + off]; }
        __syncthreads();
    }
    if (tid == 0) {
        const float n = 4.f * THW;
        float mean = rs[0] / n;
        float var = rq[0] / n - mean * mean;
        float sc = g_agg[c] * rsqrtf(var + BN_EPS);
        bna[c] = sc;
        bna[Cch + c] = b_agg[c] - mean * sc;
    }
}

// ---------------- K9: out = relu(xp + BN(Z)) ----------------
__global__ __launch_bounds__(256) void k_final(const float* __restrict__ xp,
                                               const float* __restrict__ Z,
                                               const float* __restrict__ bna,
                                               float* __restrict__ out) {
    int idx = blockIdx.x * 256 + threadIdx.x;
    if (idx >= NPIX) return;
    int c = (idx / THW) & 511;
    out[idx] = fmaxf(fmaf(Z[idx], bna[c], bna[Cch + c]) + xp[idx], 0.f);
}

extern "C" void kernel_launch(void* const* d_in, const int* in_sizes, int n_in,
                              void* d_out, int out_size, void* d_ws, size_t ws_size,
                              hipStream_t stream) {
    const float* x     = (const float*)d_in[0];
    const float* Wq    = (const float*)d_in[1];
    const float* Wm    = (const float*)d_in[2];
    const float* Wv    = (const float*)d_in[3];
    const float* Wcat  = (const float*)d_in[4];
    const float* Wsub  = (const float*)d_in[5];
    const float* Wmul  = (const float*)d_in[6];
    const float* g_cat = (const float*)d_in[7];
    const float* b_cat = (const float*)d_in[8];
    const float* g_sub = (const float*)d_in[9];
    const float* b_sub = (const float*)d_in[10];
    const float* g_mul = (const float*)d_in[11];
    const float* b_mul = (const float*)d_in[12];
    const float* Wagg  = (const float*)d_in[13];
    const float* g_agg = (const float*)d_in[14];
    const float* b_agg = (const float*)d_in[15];
    float* out = (float*)d_out;
    float* ws  = (float*)d_ws;

    // workspace layout (floats); total ~45.3M floats = 181 MB
    float* xp  = ws;                 // 7,872,512
    float* Vcl = xp  + 7872512;      // 3,936,256 fp32 channel-last (compare)
    float* Vcf = Vcl + 3936256;      // 3,936,256 fp32 channel-first (aggregate)
    float* R   = Vcf + 3936256;      // 15,745,024 (b,m,q,c)
    float* Pc  = R   + 15745024;     // 7,750,656
    float* bnc = Pc  + 7750656;      // 512
    float* bna = bnc + 512;          // 1024
    unsigned short* Qbf = (unsigned short*)(bna + 1024);  // 3,936,256 ushorts
    unsigned short* Mbf = Qbf + 3936256;                  // 3,936,256
    unsigned short* Vbf = Mbf + 3936256;                  // 16*256*1024 = 4,194,304
    float* Rm = (float*)Qbf;  // alias: Qbf+Mbf dead after attention
    float* Z  = R;            // alias: R dead after rmean+compare

    k_pool<<<dim3((NPIX + 255) / 256), dim3(256), 0, stream>>>(x, xp);
    k_qmv<<<dim3(61, 12, Bb), dim3(16, 16), 0, stream>>>(xp, Wq, Wm, Wv, Qbf, Mbf,
                                                         Vcl, Vcf, Vbf);
    k_attn_mfma<<<dim3(16, 61), dim3(256), 0, stream>>>(Qbf, Mbf, Vbf, R);
    k_rmean<<<dim3(31, 8, 16), dim3(256), 0, stream>>>(R, Rm);
    k_compare<<<dim3(31, 16, Bb), dim3(256), 0, stream>>>(R, Vcl, Wcat, Wsub, Wmul, Pc);
    k_stats_cmp<<<dim3(NCMP), dim3(256), 0, stream>>>(Pc, g_cat, b_cat, g_sub, b_sub,
                                                      g_mul, b_mul, bnc);
    k_agg<<<dim3(61, 8, Bb), dim3(16, 16), 0, stream>>>(Wagg, Rm, Vcf, Pc, bnc, Z);
    k_stats_agg<<<dim3(Cch), dim3(256), 0, stream>>>(Z, g_agg, b_agg, bna);
    k_final<<<dim3((NPIX + 255) / 256), dim3(256), 0, stream>>>(xp, Z, bna, out);
}

// Round 4
// 1159.656 us; speedup vs baseline: 8.3442x; 1.6318x over previous
//
#include <hip/hip_runtime.h>
#include <math.h>

// Problem dims
constexpr int Bb   = 4;
constexpr int Cch  = 512;
constexpr int HW   = 961;      // 31*31
constexpr int THW  = 3844;     // 4*961
constexpr int NCMP = 126;      // 3*42 compare channels
constexpr int NPIX = Bb * Cch * THW;  // 7,872,512
constexpr int Hp = 31, Wp = 31, H0c = 63, W0c = 63;
constexpr int VP = 1024;       // padded keys/frame for Vbf
#define BN_EPS 1e-5f

typedef __attribute__((ext_vector_type(4))) float floatx4;
typedef __attribute__((ext_vector_type(8))) __bf16 bf16x8;
typedef __attribute__((ext_vector_type(8))) unsigned short ushort8;
typedef __attribute__((ext_vector_type(4))) unsigned short ushort4v;

static __device__ __forceinline__ unsigned short f2bf(float x) {
    unsigned int u = __builtin_bit_cast(unsigned int, x);
    u += 0x7fff + ((u >> 16) & 1);   // RNE
    return (unsigned short)(u >> 16);
}

// ---------------- K0: pack weights to bf16 ----------------
// Wpk: [cat 48x512 | sub 48x256 | mul 48x256] (rows >=42 zero) = 49,152 us
// Wab: [512][1024] (k >= 1016 zero) = 524,288 us
__global__ __launch_bounds__(256) void k_prep_w(
    const float* __restrict__ Wcat, const float* __restrict__ Wsub,
    const float* __restrict__ Wmul, const float* __restrict__ Wagg,
    unsigned short* __restrict__ Wpk, unsigned short* __restrict__ Wab) {
    int idx = blockIdx.x * 256 + threadIdx.x;
    if (idx < 24576) {                       // cat
        int row = idx >> 9, k = idx & 511;
        Wpk[idx] = (row < 42) ? f2bf(Wcat[row * 512 + k]) : 0;
    } else if (idx < 36864) {                // sub
        int i = idx - 24576;
        int row = i >> 8, k = i & 255;
        Wpk[idx] = (row < 42) ? f2bf(Wsub[row * 256 + k]) : 0;
    } else if (idx < 49152) {                // mul
        int i = idx - 36864;
        int row = i >> 8, k = i & 255;
        Wpk[idx] = (row < 42) ? f2bf(Wmul[row * 256 + k]) : 0;
    } else if (idx < 49152 + 524288) {       // agg
        int i = idx - 49152;
        int row = i >> 10, k = i & 1023;
        Wab[i] = (k < 1016) ? f2bf(Wagg[(size_t)row * 1016 + k]) : 0;
    }
}

// ---------------- K1: maxpool (1,3,3)/(1,2,2) ----------------
__global__ __launch_bounds__(256) void k_pool(const float* __restrict__ x,
                                              float* __restrict__ xp) {
    int idx = blockIdx.x * 256 + threadIdx.x;
    if (idx >= NPIX) return;
    int w = idx % Wp;
    int h = (idx / Wp) % Hp;
    int bct = idx / HW;
    const float* src = x + (size_t)bct * (H0c * W0c) + (2 * h) * W0c + 2 * w;
    float m = -INFINITY;
    #pragma unroll
    for (int i = 0; i < 3; ++i) {
        m = fmaxf(m, src[i * W0c + 0]);
        m = fmaxf(m, src[i * W0c + 1]);
        m = fmaxf(m, src[i * W0c + 2]);
    }
    xp[idx] = m;
}

// ---------------- K2: Q/M/V projections (tiled fp32 GEMM) ----------------
// Qbf/Mbf channel-last bf16 (Q pre-scaled 1/16); Vcl fp32 channel-last;
// Vbf [bm][ch][key pad 1024] bf16 for attention.
__global__ __launch_bounds__(256) void k_qmv(
    const float* __restrict__ xp, const float* __restrict__ Wq,
    const float* __restrict__ Wm, const float* __restrict__ Wv,
    unsigned short* __restrict__ Qbf, unsigned short* __restrict__ Mbf,
    float* __restrict__ Vcl, unsigned short* __restrict__ Vbf) {
    __shared__ float Wt[16][64];
    __shared__ float Xt[16][64];
    const int p0  = blockIdx.x * 64;
    const int oc0 = blockIdx.y * 64;
    const int b   = blockIdx.z;
    const int sel = oc0 >> 8;          // 0:Q 1:M 2:V
    const int ocr = oc0 & 255;
    const float* Wbase = (sel == 0) ? Wq : (sel == 1) ? Wm : Wv;
    const int tx = threadIdx.x, ty = threadIdx.y;
    const int tid = ty * 16 + tx;
    float acc[4][4] = {{0.f}};
    for (int kc = 0; kc < 512; kc += 16) {
        __syncthreads();
        for (int l = tid; l < 1024; l += 256) {
            int kk = l & 15, j = l >> 4;
            Wt[kk][j] = Wbase[(size_t)(ocr + j) * 512 + kc + kk];
        }
        for (int l = tid; l < 1024; l += 256) {
            int pp = l & 63, kk = l >> 6;
            int p = p0 + pp;
            Xt[kk][pp] = (p < THW) ? xp[(size_t)(b * Cch + kc + kk) * THW + p] : 0.f;
        }
        __syncthreads();
        #pragma unroll
        for (int kk = 0; kk < 16; ++kk) {
            float a[4], c[4];
            *(float4*)a = *(const float4*)&Wt[kk][ty * 4];
            *(float4*)c = *(const float4*)&Xt[kk][tx * 4];
            #pragma unroll
            for (int i = 0; i < 4; ++i)
                #pragma unroll
                for (int j = 0; j < 4; ++j) acc[i][j] = fmaf(a[i], c[j], acc[i][j]);
        }
    }
    const int ocl = ocr + ty * 4;
    if (sel < 2) {
        unsigned short* outbf = (sel == 0) ? Qbf : Mbf;
        const float scale = (sel == 0) ? 0.0625f : 1.0f;
        #pragma unroll
        for (int j = 0; j < 4; ++j) {
            int p = p0 + tx * 4 + j;
            if (p < THW) {
                ushort4v v;
                #pragma unroll
                for (int i = 0; i < 4; ++i) v[i] = f2bf(acc[i][j] * scale);
                *(ushort4v*)&outbf[((size_t)b * THW + p) * 256 + ocl] = v;
            }
        }
    } else {
        #pragma unroll
        for (int j = 0; j < 4; ++j) {
            int p = p0 + tx * 4 + j;
            if (p < THW) {
                float4 v = make_float4(acc[0][j], acc[1][j], acc[2][j], acc[3][j]);
                *(float4*)&Vcl[((size_t)b * THW + p) * 256 + ocl] = v;
            }
        }
        int pb = p0 + tx * 4;
        if (pb < THW) {
            #pragma unroll
            for (int j = 0; j < 4; ++j) {
                int p = pb + j;
                int mm = p / HW, key = p - mm * HW;
                #pragma unroll
                for (int i = 0; i < 4; ++i)
                    Vbf[(((size_t)(b * 4 + mm)) * 256 + ocl + i) * VP + key] =
                        f2bf(acc[i][j]);
            }
        }
    }
}

// ---------------- K3: flash attention, bf16 MFMA, register softmax ----------------
__global__ __launch_bounds__(256, 2) void k_attn_mfma(
    const unsigned short* __restrict__ Qbf, const unsigned short* __restrict__ Mbf,
    const unsigned short* __restrict__ Vbf, float* __restrict__ R) {
    __shared__ unsigned short MV[16384] __attribute__((aligned(16)));
    __shared__ unsigned short Ps[4096] __attribute__((aligned(16)));
    __shared__ float stat_mx[4][64];
    __shared__ float stat_sm[4][64];
    __shared__ float alpha_s[64];

    const int bm = blockIdx.x;
    const int b = bm >> 2, m = bm & 3;
    const int q0 = blockIdx.y * 64;
    const int tid = threadIdx.x;
    const int wv = tid >> 6, lane = tid & 63;
    const int l15 = lane & 15, quad = lane >> 4;

    ushort8 qf[4][8];
    #pragma unroll
    for (int mt = 0; mt < 4; ++mt) {
        int q = q0 + mt * 16 + l15;
        #pragma unroll
        for (int kci = 0; kci < 8; ++kci) {
            ushort8 v = {0, 0, 0, 0, 0, 0, 0, 0};
            if (q < THW)
                v = *(const ushort8*)&Qbf[((size_t)b * THW + q) * 256 + kci * 32 + quad * 8];
            qf[mt][kci] = v;
        }
    }
    floatx4 o[4][4];
    #pragma unroll
    for (int mt = 0; mt < 4; ++mt)
        #pragma unroll
        for (int nt = 0; nt < 4; ++nt) o[mt][nt] = (floatx4){0.f, 0.f, 0.f, 0.f};
    float m_run[4], l_run[4];
    #pragma unroll
    for (int mt = 0; mt < 4; ++mt) { m_run[mt] = -1e30f; l_run[mt] = 0.f; }

    const size_t mbase = ((size_t)b * THW + m * HW) * 256;
    const size_t vb = (size_t)bm * 256 * VP;

    for (int kt = 0; kt < 16; ++kt) {
        const int k0 = kt * 64;
        int nv = HW - k0; if (nv > 64) nv = 64;
        __syncthreads();
        #pragma unroll
        for (int it = 0; it < 8; ++it) {
            int v = it * 256 + tid;
            int key = v >> 5, ck = v & 31;
            ushort8 val = {0, 0, 0, 0, 0, 0, 0, 0};
            if (key < nv)
                val = *(const ushort8*)&Mbf[mbase + (size_t)(k0 + key) * 256 + ck * 8];
            *(ushort8*)&MV[key * 256 + ((ck ^ (key & 7)) << 3)] = val;
        }
        __syncthreads();
        floatx4 sc[4];
        #pragma unroll
        for (int mt = 0; mt < 4; ++mt) sc[mt] = (floatx4){0.f, 0.f, 0.f, 0.f};
        const int mkey = wv * 16 + l15;
        #pragma unroll
        for (int kci = 0; kci < 8; ++kci) {
            ushort8 mf = *(const ushort8*)&MV[mkey * 256 + (((kci * 4 + quad) ^ (mkey & 7)) << 3)];
            #pragma unroll
            for (int mt = 0; mt < 4; ++mt)
                sc[mt] = __builtin_amdgcn_mfma_f32_16x16x32_bf16(
                    __builtin_bit_cast(bf16x8, mf),
                    __builtin_bit_cast(bf16x8, qf[mt][kci]), sc[mt], 0, 0, 0);
        }
        #pragma unroll
        for (int r = 0; r < 4; ++r) {
            if (wv * 16 + quad * 4 + r >= nv) {
                #pragma unroll
                for (int mt = 0; mt < 4; ++mt) sc[mt][r] = -1e30f;
            }
        }
        float mx[4], sm[4];
        #pragma unroll
        for (int mt = 0; mt < 4; ++mt) {
            float v = fmaxf(fmaxf(sc[mt][0], sc[mt][1]), fmaxf(sc[mt][2], sc[mt][3]));
            v = fmaxf(v, __shfl_xor(v, 16));
            v = fmaxf(v, __shfl_xor(v, 32));
            mx[mt] = v;
        }
        #pragma unroll
        for (int mt = 0; mt < 4; ++mt) {
            float s = 0.f;
            #pragma unroll
            for (int r = 0; r < 4; ++r) {
                bool oob = (wv * 16 + quad * 4 + r) >= nv;
                float p = oob ? 0.f : __expf(sc[mt][r] - mx[mt]);
                sc[mt][r] = p;
                s += p;
            }
            s += __shfl_xor(s, 16);
            s += __shfl_xor(s, 32);
            sm[mt] = s;
        }
        if (quad == 0) {
            #pragma unroll
            for (int mt = 0; mt < 4; ++mt) {
                stat_mx[wv][mt * 16 + l15] = mx[mt];
                stat_sm[wv][mt * 16 + l15] = sm[mt];
            }
        }
        __syncthreads();
        float fown[4];
        #pragma unroll
        for (int mt = 0; mt < 4; ++mt) {
            int qrow = mt * 16 + l15;
            float m0 = stat_mx[0][qrow], m1 = stat_mx[1][qrow];
            float m2 = stat_mx[2][qrow], m3 = stat_mx[3][qrow];
            float gmax = fmaxf(fmaxf(m0, m1), fmaxf(m2, m3));
            float mn = fmaxf(m_run[mt], gmax);
            float al = __expf(m_run[mt] - mn);
            float e0 = __expf(m0 - mn), e1 = __expf(m1 - mn);
            float e2 = __expf(m2 - mn), e3 = __expf(m3 - mn);
            l_run[mt] = l_run[mt] * al + stat_sm[0][qrow] * e0 + stat_sm[1][qrow] * e1
                      + stat_sm[2][qrow] * e2 + stat_sm[3][qrow] * e3;
            m_run[mt] = mn;
            fown[mt] = (wv == 0) ? e0 : (wv == 1) ? e1 : (wv == 2) ? e2 : e3;
            if (wv == 0 && quad == 0) alpha_s[qrow] = al;
        }
        #pragma unroll
        for (int mt = 0; mt < 4; ++mt) {
            int qrow = mt * 16 + l15;
            int base = qrow * 64;
            #pragma unroll
            for (int r = 0; r < 4; ++r) {
                int key = wv * 16 + quad * 4 + r;
                Ps[base + (((key >> 3) ^ (qrow & 7)) << 3) + (key & 7)] =
                    f2bf(sc[mt][r] * fown[mt]);
            }
        }
        #pragma unroll
        for (int it = 0; it < 8; ++it) {
            int u = it * 256 + tid;
            int ch = u >> 3, k8 = (u & 7) << 3;
            ushort8 val = *(const ushort8*)&Vbf[vb + (size_t)ch * VP + k0 + k8];
            *(ushort8*)&MV[ch * 64 + (((k8 >> 3) ^ (ch & 7)) << 3)] = val;
        }
        __syncthreads();
        #pragma unroll
        for (int mt = 0; mt < 4; ++mt) {
            float al[4];
            #pragma unroll
            for (int r = 0; r < 4; ++r) al[r] = alpha_s[mt * 16 + quad * 4 + r];
            #pragma unroll
            for (int nt = 0; nt < 4; ++nt)
                #pragma unroll
                for (int r = 0; r < 4; ++r) o[mt][nt][r] *= al[r];
        }
        #pragma unroll
        for (int ks = 0; ks < 2; ++ks) {
            ushort8 af[4];
            #pragma unroll
            for (int mt = 0; mt < 4; ++mt) {
                int row = mt * 16 + l15;
                af[mt] = *(const ushort8*)&Ps[row * 64 + (((ks * 4 + quad) ^ (row & 7)) << 3)];
            }
            #pragma unroll
            for (int nt = 0; nt < 4; ++nt) {
                int ch = wv * 64 + nt * 16 + l15;
                ushort8 bv = *(const ushort8*)&MV[ch * 64 + (((ks * 4 + quad) ^ (ch & 7)) << 3)];
                #pragma unroll
                for (int mt = 0; mt < 4; ++mt)
                    o[mt][nt] = __builtin_amdgcn_mfma_f32_16x16x32_bf16(
                        __builtin_bit_cast(bf16x8, af[mt]),
                        __builtin_bit_cast(bf16x8, bv), o[mt][nt], 0, 0, 0);
            }
        }
    }
    if (wv == 0 && quad == 0) {
        #pragma unroll
        for (int mt = 0; mt < 4; ++mt) stat_mx[0][mt * 16 + l15] = l_run[mt];
    }
    __syncthreads();
    #pragma unroll
    for (int mt = 0; mt < 4; ++mt) {
        float invl[4];
        #pragma unroll
        for (int r = 0; r < 4; ++r) invl[r] = 1.f / stat_mx[0][mt * 16 + quad * 4 + r];
        #pragma unroll
        for (int nt = 0; nt < 4; ++nt) {
            int ch = wv * 64 + nt * 16 + l15;
            #pragma unroll
            for (int r = 0; r < 4; ++r) {
                int q = q0 + mt * 16 + quad * 4 + r;
                if (q < THW)
                    R[(((size_t)bm) * THW + q) * 256 + ch] = o[mt][nt][r] * invl[r];
            }
        }
    }
}

// ---------------- K5: compare convs via MFMA ----------------
// grid (8 strips of 128px, 16 s, 8 = b*2+kind). kind 0: cat; kind 1: sub+mul.
// A = weights (rows=ci) from LDS (swizzled); B = feature frags built in-register.
__global__ __launch_bounds__(256) void k_cmp(
    const float* __restrict__ R, const float* __restrict__ Vcl,
    const unsigned short* __restrict__ Wpk, float* __restrict__ Pc) {
    __shared__ unsigned short Ws[24576] __attribute__((aligned(16)));  // 48 KB
    const int strip = blockIdx.x;
    const int s = blockIdx.y;
    const int b = blockIdx.z >> 1, kind = blockIdx.z & 1;
    const int m = s >> 2, tq = s & 3;
    const int tid = threadIdx.x;
    const int wv = tid >> 6, lane = tid & 63;
    const int l15 = lane & 15, quad = lane >> 4;

    // stage weights with chunk swizzle (row-dependent xor on 8-elem chunks)
    const unsigned short* wsrc = Wpk + (kind ? 24576 : 0);
    for (int i = tid; i < 3072; i += 256) {
        int row, ch, stride_us;
        if (kind == 0) { row = i >> 6; ch = i & 63; stride_us = 512; }
        else           { row = i >> 5; ch = i & 31; stride_us = 256; }
        ushort8 v = *(const ushort8*)&wsrc[i * 8];
        *(ushort8*)&Ws[row * stride_us + ((ch ^ (row & 7)) << 3)] = v;
    }
    __syncthreads();

    const size_t rbase = ((size_t)(b * 4 + m) * THW + tq * HW) * 256;
    const size_t vbase = ((size_t)b * THW + m * HW) * 256;

    #pragma unroll
    for (int half = 0; half < 2; ++half) {
        int pxt = wv * 2 + half;
        int hw = strip * 128 + pxt * 16 + l15;
        int hwc = min(hw, HW - 1);
        const float* rrow = R + rbase + (size_t)hwc * 256;
        const float* vrow = Vcl + vbase + (size_t)hwc * 256;
        bf16x8 fr[8], fs[8];   // kind0: R,V ; kind1: D,P
        #pragma unroll
        for (int ks = 0; ks < 8; ++ks) {
            float rv[8], vv[8];
            *(float4*)&rv[0] = *(const float4*)&rrow[ks * 32 + quad * 8];
            *(float4*)&rv[4] = *(const float4*)&rrow[ks * 32 + quad * 8 + 4];
            *(float4*)&vv[0] = *(const float4*)&vrow[ks * 32 + quad * 8];
            *(float4*)&vv[4] = *(const float4*)&vrow[ks * 32 + quad * 8 + 4];
            bf16x8 a, c;
            if (kind == 0) {
                #pragma unroll
                for (int j = 0; j < 8; ++j) { a[j] = (__bf16)rv[j]; c[j] = (__bf16)vv[j]; }
            } else {
                #pragma unroll
                for (int j = 0; j < 8; ++j) {
                    a[j] = (__bf16)(rv[j] - vv[j]);
                    c[j] = (__bf16)(rv[j] * vv[j]);
                }
            }
            fr[ks] = a; fs[ks] = c;
        }
        floatx4 acc[6];
        #pragma unroll
        for (int i = 0; i < 6; ++i) acc[i] = (floatx4){0.f, 0.f, 0.f, 0.f};
        if (kind == 0) {
            #pragma unroll
            for (int ks = 0; ks < 16; ++ks) {
                bf16x8 bfr = (ks < 8) ? fr[ks] : fs[ks - 8];
                #pragma unroll
                for (int cit = 0; cit < 3; ++cit) {
                    int row = cit * 16 + l15;
                    ushort8 aw = *(const ushort8*)&Ws[row * 512 + (((ks * 4 + quad) ^ (row & 7)) << 3)];
                    acc[cit] = __builtin_amdgcn_mfma_f32_16x16x32_bf16(
                        __builtin_bit_cast(bf16x8, aw), bfr, acc[cit], 0, 0, 0);
                }
            }
        } else {
            #pragma unroll
            for (int ks = 0; ks < 8; ++ks) {
                #pragma unroll
                for (int cit = 0; cit < 6; ++cit) {
                    int row = cit * 16 + l15;
                    ushort8 aw = *(const ushort8*)&Ws[row * 256 + (((ks * 4 + quad) ^ (row & 7)) << 3)];
                    bf16x8 bfr = (cit < 3) ? fr[ks] : fs[ks];
                    acc[cit] = __builtin_amdgcn_mfma_f32_16x16x32_bf16(
                        __builtin_bit_cast(bf16x8, aw), bfr, acc[cit], 0, 0, 0);
                }
            }
        }
        if (hw < HW) {
            if (kind == 0) {
                #pragma unroll
                for (int cit = 0; cit < 3; ++cit)
                    #pragma unroll
                    for (int r = 0; r < 4; ++r) {
                        int ci = cit * 16 + quad * 4 + r;
                        if (ci < 42)
                            Pc[((size_t)(b * NCMP + ci) * 16 + s) * HW + hw] = acc[cit][r];
                    }
            } else {
                #pragma unroll
                for (int cit = 0; cit < 6; ++cit)
                    #pragma unroll
                    for (int r = 0; r < 4; ++r) {
                        int cl = (cit % 3) * 16 + quad * 4 + r;
                        if (cl < 42) {
                            int ci = (cit < 3 ? 42 : 84) + cl;
                            Pc[((size_t)(b * NCMP + ci) * 16 + s) * HW + hw] = acc[cit][r];
                        }
                    }
            }
        }
    }
}

// ---------------- K6: BN stats for compare ----------------
__global__ __launch_bounds__(256) void k_stats_cmp(
    const float* __restrict__ Pc, const float* __restrict__ g_cat,
    const float* __restrict__ b_cat, const float* __restrict__ g_sub,
    const float* __restrict__ b_sub, const float* __restrict__ g_mul,
    const float* __restrict__ b_mul, float* __restrict__ bnc) {
    const int c = blockIdx.x, tid = threadIdx.x;
    float s = 0.f, q = 0.f;
    for (int i = tid; i < 4 * 16 * HW; i += 256) {
        int bb = i / (16 * HW), r = i - bb * (16 * HW);
        float v = Pc[(size_t)(bb * NCMP + c) * (16 * HW) + r];
        s += v; q += v * v;
    }
    __shared__ float rs[256], rq[256];
    rs[tid] = s; rq[tid] = q;
    __syncthreads();
    for (int off = 128; off > 0; off >>= 1) {
        if (tid < off) { rs[tid] += rs[tid + off]; rq[tid] += rq[tid + off]; }
        __syncthreads();
    }
    if (tid == 0) {
        const float n = 4.f * 16.f * HW;
        float mean = rs[0] / n;
        float var = rq[0] / n - mean * mean;
        float g, bt;
        if (c < 42)       { g = g_cat[c];      bt = b_cat[c]; }
        else if (c < 84)  { g = g_sub[c - 42]; bt = b_sub[c - 42]; }
        else              { g = g_mul[c - 84]; bt = b_mul[c - 84]; }
        float sc = g * rsqrtf(var + BN_EPS);
        bnc[c] = sc;
        bnc[NCMP + c] = bt - mean * sc;
    }
}

// ---------------- K7: build Y channel-last bf16 [b][p][1024] ----------------
// ch 0-255: Rmean(t as m); 256-511: V; 512-1015: relu(BN(Pc)) ch=512+ci*4+mm; 1016+: 0
__global__ __launch_bounds__(256) void k_build_y(
    const float* __restrict__ R, const float* __restrict__ Vcl,
    const float* __restrict__ Pc, const float* __restrict__ bnc,
    unsigned short* __restrict__ Ybf) {
    const int strip = blockIdx.x, t = blockIdx.y, b = blockIdx.z;
    const int tid = threadIdx.x;
    const int chl = tid & 31;      // 32 lanes x 4ch = 128 ch per cb-iter
    const int hwl = tid >> 5;      // 8 hw rows per pass
    for (int pass = 0; pass < 8; ++pass) {
        int hw = strip * 64 + pass * 8 + hwl;
        if (hw >= HW) continue;
        size_t ybase = ((size_t)b * THW + t * HW + hw) * 1024;
        for (int cb = 0; cb < 8; ++cb) {
            int ch = cb * 128 + chl * 4;
            float v[4];
            if (ch < 256) {
                float4 sacc = make_float4(0.f, 0.f, 0.f, 0.f);
                #pragma unroll
                for (int tq = 0; tq < 4; ++tq) {
                    float4 rv = *(const float4*)&R[(((size_t)(b * 4 + t)) * THW + tq * HW + hw) * 256 + ch];
                    sacc.x += rv.x; sacc.y += rv.y; sacc.z += rv.z; sacc.w += rv.w;
                }
                v[0] = sacc.x * 0.25f; v[1] = sacc.y * 0.25f;
                v[2] = sacc.z * 0.25f; v[3] = sacc.w * 0.25f;
            } else if (ch < 512) {
                float4 vv = *(const float4*)&Vcl[((size_t)b * THW + t * HW + hw) * 256 + (ch - 256)];
                v[0] = vv.x; v[1] = vv.y; v[2] = vv.z; v[3] = vv.w;
            } else if (ch < 1016) {
                int ci = (ch - 512) >> 2;
                float sc = bnc[ci], sh = bnc[NCMP + ci];
                #pragma unroll
                for (int mm = 0; mm < 4; ++mm) {
                    float pv = Pc[(((size_t)(b * NCMP + ci)) * 16 + mm * 4 + t) * HW + hw];
                    v[mm] = fmaxf(fmaf(pv, sc, sh), 0.f);
                }
            } else {
                v[0] = v[1] = v[2] = v[3] = 0.f;
            }
            ushort4v o;
            #pragma unroll
            for (int i = 0; i < 4; ++i) o[i] = f2bf(v[i]);
            *(ushort4v*)&Ybf[ybase + ch] = o;
        }
    }
}

// ---------------- K8: aggregate GEMM via MFMA ----------------
// grid (31 strips of 128px, 4 oc-blocks of 128, 4 b)
__global__ __launch_bounds__(256) void k_aggm(
    const unsigned short* __restrict__ Wab, const unsigned short* __restrict__ Ybf,
    float* __restrict__ Z) {
    __shared__ unsigned short Wt[16384] __attribute__((aligned(16)));  // 32 KB
    const int p0 = blockIdx.x * 128;
    const int oc0 = blockIdx.y * 128;
    const int b = blockIdx.z;
    const int tid = threadIdx.x;
    const int wv = tid >> 6, lane = tid & 63;
    const int l15 = lane & 15, quad = lane >> 4;
    floatx4 acc[8][2];
    #pragma unroll
    for (int i = 0; i < 8; ++i)
        #pragma unroll
        for (int h = 0; h < 2; ++h) acc[i][h] = (floatx4){0.f, 0.f, 0.f, 0.f};
    for (int kc = 0; kc < 8; ++kc) {
        __syncthreads();
        for (int i = tid; i < 2048; i += 256) {
            int row = i >> 4, ch = i & 15;
            ushort8 v = *(const ushort8*)&Wab[(size_t)(oc0 + row) * 1024 + kc * 128 + ch * 8];
            *(ushort8*)&Wt[row * 128 + ((ch ^ (row & 7)) << 3)] = v;
        }
        __syncthreads();
        #pragma unroll
        for (int half = 0; half < 2; ++half) {
            int px = p0 + (wv * 2 + half) * 16 + l15;
            int pxc = min(px, THW - 1);
            const unsigned short* yrow = Ybf + ((size_t)b * THW + pxc) * 1024 + kc * 128;
            #pragma unroll
            for (int ks = 0; ks < 4; ++ks) {
                ushort8 bf = *(const ushort8*)&yrow[ks * 32 + quad * 8];
                #pragma unroll
                for (int oct = 0; oct < 8; ++oct) {
                    int row = oct * 16 + l15;
                    ushort8 af = *(const ushort8*)&Wt[row * 128 + ((((ks * 4 + quad) ^ (row & 7))) << 3)];
                    acc[oct][half] = __builtin_amdgcn_mfma_f32_16x16x32_bf16(
                        __builtin_bit_cast(bf16x8, af),
                        __builtin_bit_cast(bf16x8, bf), acc[oct][half], 0, 0, 0);
                }
            }
        }
    }
    #pragma unroll
    for (int half = 0; half < 2; ++half) {
        int px = p0 + (wv * 2 + half) * 16 + l15;
        if (px < THW) {
            #pragma unroll
            for (int oct = 0; oct < 8; ++oct) {
                int oc = oc0 + oct * 16 + quad * 4;
                #pragma unroll
                for (int r = 0; r < 4; ++r)
                    Z[((size_t)(b * Cch + oc + r)) * THW + px] = acc[oct][half][r];
            }
        }
    }
}

// ---------------- K9: BN stats for aggregate ----------------
__global__ __launch_bounds__(256) void k_stats_agg(
    const float* __restrict__ Z, const float* __restrict__ g_agg,
    const float* __restrict__ b_agg, float* __restrict__ bna) {
    const int c = blockIdx.x, tid = threadIdx.x;
    float s = 0.f, q = 0.f;
    for (int i = tid; i < 4 * THW; i += 256) {
        int bb = i / THW, p = i - bb * THW;
        float v = Z[((size_t)bb * Cch + c) * THW + p];
        s += v; q += v * v;
    }
    __shared__ float rs[256], rq[256];
    rs[tid] = s; rq[tid] = q;
    __syncthreads();
    for (int off = 128; off > 0; off >>= 1) {
        if (tid < off) { rs[tid] += rs[tid + off]; rq[tid] += rq[tid + off]; }
        __syncthreads();
    }
    if (tid == 0) {
        const float n = 4.f * THW;
        float mean = rs[0] / n;
        float var = rq[0] / n - mean * mean;
        float sc = g_agg[c] * rsqrtf(var + BN_EPS);
        bna[c] = sc;
        bna[Cch + c] = b_agg[c] - mean * sc;
    }
}

// ---------------- K10: out = relu(xp + BN(Z)) ----------------
__global__ __launch_bounds__(256) void k_final(const float* __restrict__ xp,
                                               const float* __restrict__ Z,
                                               const float* __restrict__ bna,
                                               float* __restrict__ out) {
    int idx = blockIdx.x * 256 + threadIdx.x;
    if (idx >= NPIX) return;
    int c = (idx / THW) & 511;
    out[idx] = fmaxf(fmaf(Z[idx], bna[c], bna[Cch + c]) + xp[idx], 0.f);
}

extern "C" void kernel_launch(void* const* d_in, const int* in_sizes, int n_in,
                              void* d_out, int out_size, void* d_ws, size_t ws_size,
                              hipStream_t stream) {
    const float* x     = (const float*)d_in[0];
    const float* Wq    = (const float*)d_in[1];
    const float* Wm    = (const float*)d_in[2];
    const float* Wv    = (const float*)d_in[3];
    const float* Wcat  = (const float*)d_in[4];
    const float* Wsub  = (const float*)d_in[5];
    const float* Wmul  = (const float*)d_in[6];
    const float* g_cat = (const float*)d_in[7];
    const float* b_cat = (const float*)d_in[8];
    const float* g_sub = (const float*)d_in[9];
    const float* b_sub = (const float*)d_in[10];
    const float* g_mul = (const float*)d_in[11];
    const float* b_mul = (const float*)d_in[12];
    const float* Wagg  = (const float*)d_in[13];
    const float* g_agg = (const float*)d_in[14];
    const float* b_agg = (const float*)d_in[15];
    float* out = (float*)d_out;
    float* ws  = (float*)d_ws;

    // workspace layout (float offsets); total 43,465,216 fl = 173.9 MB
    float* xp  = ws;                          // 7,872,512
    float* Vcl = xp + 7872512;                // 3,936,256
    float* R   = Vcl + 3936256;               // 15,745,024 (Z aliases)
    float* Pc  = R + 15745024;                // 7,750,656
    float* bnc = Pc + 7750656;                // 512
    float* bna = bnc + 512;                   // 1024
    float* bfreg = bna + 1024;                // 7,872,512 fl region
    unsigned short* Qbf = (unsigned short*)bfreg;        // 3,936,256 us
    unsigned short* Mbf = Qbf + 3936256;                 // 3,936,256 us
    unsigned short* Vbf = Mbf + 3936256;                 // 4,194,304 us
    unsigned short* Ybf = (unsigned short*)bfreg;        // alias (Q/M/V dead): 15,745,024 us
    unsigned short* Wpk = (unsigned short*)(bfreg + 7872512);  // 49,152 us = 24,576 fl
    unsigned short* Wab = Wpk + 49152;                   // 524,288 us = 262,144 fl
    float* Z = R;  // alias: R dead after build_y

    k_prep_w<<<dim3(2240), dim3(256), 0, stream>>>(Wcat, Wsub, Wmul, Wagg, Wpk, Wab);
    k_pool<<<dim3((NPIX + 255) / 256), dim3(256), 0, stream>>>(x, xp);
    k_qmv<<<dim3(61, 12, Bb), dim3(16, 16), 0, stream>>>(xp, Wq, Wm, Wv, Qbf, Mbf,
                                                         Vcl, Vbf);
    k_attn_mfma<<<dim3(16, 61), dim3(256), 0, stream>>>(Qbf, Mbf, Vbf, R);
    k_cmp<<<dim3(8, 16, 8), dim3(256), 0, stream>>>(R, Vcl, Wpk, Pc);
    k_stats_cmp<<<dim3(NCMP), dim3(256), 0, stream>>>(Pc, g_cat, b_cat, g_sub, b_sub,
                                                      g_mul, b_mul, bnc);
    k_build_y<<<dim3(16, 4, Bb), dim3(256), 0, stream>>>(R, Vcl, Pc, bnc, Ybf);
    k_aggm<<<dim3(31, 4, Bb), dim3(256), 0, stream>>>(Wab, Ybf, Z);
    k_stats_agg<<<dim3(Cch), dim3(256), 0, stream>>>(Z, g_agg, b_agg, bna);
    k_final<<<dim3((NPIX + 255) / 256), dim3(256), 0, stream>>>(xp, Z, bna, out);
}

// Round 5
// 858.602 us; speedup vs baseline: 11.2700x; 1.3506x over previous
//
#include <hip/hip_runtime.h>
#include <math.h>

// Problem dims
constexpr int Bb   = 4;
constexpr int Cch  = 512;
constexpr int HW   = 961;      // 31*31
constexpr int THW  = 3844;     // 4*961
constexpr int NCMP = 126;      // 3*42 compare channels
constexpr int NPIX = Bb * Cch * THW;  // 7,872,512
constexpr int Hp = 31, Wp = 31, H0c = 63, W0c = 63;
constexpr int VP = 1024;       // padded keys/frame for Vbf
#define BN_EPS 1e-5f

typedef __attribute__((ext_vector_type(4))) float floatx4;
typedef __attribute__((ext_vector_type(8))) __bf16 bf16x8;
typedef __attribute__((ext_vector_type(8))) unsigned short ushort8;
typedef __attribute__((ext_vector_type(4))) unsigned short ushort4v;

static __device__ __forceinline__ unsigned short f2bf(float x) {
    unsigned int u = __builtin_bit_cast(unsigned int, x);
    u += 0x7fff + ((u >> 16) & 1);   // RNE
    return (unsigned short)(u >> 16);
}
static __device__ __forceinline__ float bf2f(unsigned short u) {
    return __builtin_bit_cast(float, ((unsigned int)u) << 16);
}

// ---------------- K0: pack weights to bf16 ----------------
__global__ __launch_bounds__(256) void k_prep_w(
    const float* __restrict__ Wcat, const float* __restrict__ Wsub,
    const float* __restrict__ Wmul, const float* __restrict__ Wagg,
    unsigned short* __restrict__ Wpk, unsigned short* __restrict__ Wab) {
    int idx = blockIdx.x * 256 + threadIdx.x;
    if (idx < 24576) {                       // cat
        int row = idx >> 9, k = idx & 511;
        Wpk[idx] = (row < 42) ? f2bf(Wcat[row * 512 + k]) : 0;
    } else if (idx < 36864) {                // sub
        int i = idx - 24576;
        int row = i >> 8, k = i & 255;
        Wpk[idx] = (row < 42) ? f2bf(Wsub[row * 256 + k]) : 0;
    } else if (idx < 49152) {                // mul
        int i = idx - 36864;
        int row = i >> 8, k = i & 255;
        Wpk[idx] = (row < 42) ? f2bf(Wmul[row * 256 + k]) : 0;
    } else if (idx < 49152 + 524288) {       // agg
        int i = idx - 49152;
        int row = i >> 10, k = i & 1023;
        Wab[i] = (k < 1016) ? f2bf(Wagg[(size_t)row * 1016 + k]) : 0;
    }
}

// ---------------- K1: maxpool (1,3,3)/(1,2,2) ----------------
__global__ __launch_bounds__(256) void k_pool(const float* __restrict__ x,
                                              float* __restrict__ xp) {
    int idx = blockIdx.x * 256 + threadIdx.x;
    if (idx >= NPIX) return;
    int w = idx % Wp;
    int h = (idx / Wp) % Hp;
    int bct = idx / HW;
    const float* src = x + (size_t)bct * (H0c * W0c) + (2 * h) * W0c + 2 * w;
    float m = -INFINITY;
    #pragma unroll
    for (int i = 0; i < 3; ++i) {
        m = fmaxf(m, src[i * W0c + 0]);
        m = fmaxf(m, src[i * W0c + 1]);
        m = fmaxf(m, src[i * W0c + 2]);
    }
    xp[idx] = m;
}

// ---------------- K2: Q/M/V projections (tiled fp32 GEMM) ----------------
__global__ __launch_bounds__(256) void k_qmv(
    const float* __restrict__ xp, const float* __restrict__ Wq,
    const float* __restrict__ Wm, const float* __restrict__ Wv,
    unsigned short* __restrict__ Qbf, unsigned short* __restrict__ Mbf,
    float* __restrict__ Vcl, unsigned short* __restrict__ Vbf) {
    __shared__ float Wt[16][64];
    __shared__ float Xt[16][64];
    const int p0  = blockIdx.x * 64;
    const int oc0 = blockIdx.y * 64;
    const int b   = blockIdx.z;
    const int sel = oc0 >> 8;          // 0:Q 1:M 2:V
    const int ocr = oc0 & 255;
    const float* Wbase = (sel == 0) ? Wq : (sel == 1) ? Wm : Wv;
    const int tx = threadIdx.x, ty = threadIdx.y;
    const int tid = ty * 16 + tx;
    float acc[4][4] = {{0.f}};
    for (int kc = 0; kc < 512; kc += 16) {
        __syncthreads();
        for (int l = tid; l < 1024; l += 256) {
            int kk = l & 15, j = l >> 4;
            Wt[kk][j] = Wbase[(size_t)(ocr + j) * 512 + kc + kk];
        }
        for (int l = tid; l < 1024; l += 256) {
            int pp = l & 63, kk = l >> 6;
            int p = p0 + pp;
            Xt[kk][pp] = (p < THW) ? xp[(size_t)(b * Cch + kc + kk) * THW + p] : 0.f;
        }
        __syncthreads();
        #pragma unroll
        for (int kk = 0; kk < 16; ++kk) {
            float a[4], c[4];
            *(float4*)a = *(const float4*)&Wt[kk][ty * 4];
            *(float4*)c = *(const float4*)&Xt[kk][tx * 4];
            #pragma unroll
            for (int i = 0; i < 4; ++i)
                #pragma unroll
                for (int j = 0; j < 4; ++j) acc[i][j] = fmaf(a[i], c[j], acc[i][j]);
        }
    }
    const int ocl = ocr + ty * 4;
    if (sel < 2) {
        unsigned short* outbf = (sel == 0) ? Qbf : Mbf;
        const float scale = (sel == 0) ? 0.0625f : 1.0f;
        #pragma unroll
        for (int j = 0; j < 4; ++j) {
            int p = p0 + tx * 4 + j;
            if (p < THW) {
                ushort4v v;
                #pragma unroll
                for (int i = 0; i < 4; ++i) v[i] = f2bf(acc[i][j] * scale);
                *(ushort4v*)&outbf[((size_t)b * THW + p) * 256 + ocl] = v;
            }
        }
    } else {
        #pragma unroll
        for (int j = 0; j < 4; ++j) {
            int p = p0 + tx * 4 + j;
            if (p < THW) {
                float4 v = make_float4(acc[0][j], acc[1][j], acc[2][j], acc[3][j]);
                *(float4*)&Vcl[((size_t)b * THW + p) * 256 + ocl] = v;
            }
        }
        int pb = p0 + tx * 4;
        if (pb < THW) {
            #pragma unroll
            for (int j = 0; j < 4; ++j) {
                int p = pb + j;
                int mm = p / HW, key = p - mm * HW;
                #pragma unroll
                for (int i = 0; i < 4; ++i)
                    Vbf[(((size_t)(b * 4 + mm)) * 256 + ocl + i) * VP + key] =
                        f2bf(acc[i][j]);
            }
        }
    }
}

// ---------------- K3: flash attention, register-prefetch pipeline ----------------
// grid (16, 61): x = b*4+m, y = q-tile. R output bf16 channel-last, nontemporal.
__global__ __launch_bounds__(256, 2) void k_attn_mfma(
    const unsigned short* __restrict__ Qbf, const unsigned short* __restrict__ Mbf,
    const unsigned short* __restrict__ Vbf, unsigned short* __restrict__ Rbf) {
    // LDS: Qs 32KB + MV 32KB + Ps 8KB + stats ~2.8KB = 76.3 KB -> 2 blocks/CU
    __shared__ unsigned short Qs[16384] __attribute__((aligned(16)));
    __shared__ unsigned short MV[16384] __attribute__((aligned(16)));
    __shared__ unsigned short Ps[4096] __attribute__((aligned(16)));
    __shared__ float stat_mx[4][64];
    __shared__ float stat_sm[4][64];
    __shared__ float alpha_s[64];
    __shared__ float l_s[64];

    const int bm = blockIdx.x;
    const int b = bm >> 2, m = bm & 3;
    const int q0 = blockIdx.y * 64;
    const int tid = threadIdx.x;
    const int wv = tid >> 6, lane = tid & 63;
    const int l15 = lane & 15, quad = lane >> 4;

    const size_t mbase = ((size_t)b * THW + m * HW) * 256;
    const size_t vb = (size_t)bm * 256 * VP;

    // stage Q tile -> Qs [row][256ch], chunk swizzle ^(row&7)
    #pragma unroll
    for (int it = 0; it < 8; ++it) {
        int v = it * 256 + tid;
        int row = v >> 5, ck = v & 31;
        int q = q0 + row;
        ushort8 val = {0, 0, 0, 0, 0, 0, 0, 0};
        if (q < THW) val = *(const ushort8*)&Qbf[((size_t)b * THW + q) * 256 + ck * 8];
        *(ushort8*)&Qs[row * 256 + ((ck ^ (row & 7)) << 3)] = val;
    }
    // prefetch M(0) into regs (tile 0 is always full: HW > 64)
    ushort8 mpre[8];
    #pragma unroll
    for (int it = 0; it < 8; ++it) {
        int v = it * 256 + tid;
        int key = v >> 5, ck = v & 31;
        mpre[it] = *(const ushort8*)&Mbf[mbase + (size_t)key * 256 + ck * 8];
    }
    floatx4 o[4][4];
    #pragma unroll
    for (int mt = 0; mt < 4; ++mt)
        #pragma unroll
        for (int nt = 0; nt < 4; ++nt) o[mt][nt] = (floatx4){0.f, 0.f, 0.f, 0.f};
    float m_run[4], l_run[4];
    #pragma unroll
    for (int mt = 0; mt < 4; ++mt) { m_run[mt] = -1e30f; l_run[mt] = 0.f; }

    __syncthreads();   // Qs visible
    // commit M(0)
    #pragma unroll
    for (int it = 0; it < 8; ++it) {
        int v = it * 256 + tid;
        int key = v >> 5, ck = v & 31;
        *(ushort8*)&MV[key * 256 + ((ck ^ (key & 7)) << 3)] = mpre[it];
    }
    // prefetch V(0)
    ushort8 vpre[8];
    #pragma unroll
    for (int it = 0; it < 8; ++it) {
        int u = it * 256 + tid;
        int ch = u >> 3, k8 = (u & 7) << 3;
        vpre[it] = *(const ushort8*)&Vbf[vb + (size_t)ch * VP + k8];
    }
    __syncthreads();   // M(0) visible

    for (int kt = 0; kt < 16; ++kt) {
        const int k0 = kt * 64;
        const int nv = min(64, HW - k0);
        // QK: C[key_local][query], operands from LDS
        floatx4 sc[4];
        #pragma unroll
        for (int mt = 0; mt < 4; ++mt) sc[mt] = (floatx4){0.f, 0.f, 0.f, 0.f};
        const int mkey = wv * 16 + l15;
        #pragma unroll
        for (int kci = 0; kci < 8; ++kci) {
            ushort8 mf = *(const ushort8*)&MV[mkey * 256 + (((kci * 4 + quad) ^ (mkey & 7)) << 3)];
            #pragma unroll
            for (int mt = 0; mt < 4; ++mt) {
                int qrow = mt * 16 + l15;
                ushort8 qv = *(const ushort8*)&Qs[qrow * 256 + (((kci * 4 + quad) ^ (qrow & 7)) << 3)];
                sc[mt] = __builtin_amdgcn_mfma_f32_16x16x32_bf16(
                    __builtin_bit_cast(bf16x8, mf),
                    __builtin_bit_cast(bf16x8, qv), sc[mt], 0, 0, 0);
            }
        }
        // mask OOB keys
        #pragma unroll
        for (int r = 0; r < 4; ++r) {
            if (wv * 16 + quad * 4 + r >= nv) {
                #pragma unroll
                for (int mt = 0; mt < 4; ++mt) sc[mt][r] = -1e30f;
            }
        }
        // per-strip max/sum
        float mx[4], sm[4];
        #pragma unroll
        for (int mt = 0; mt < 4; ++mt) {
            float v = fmaxf(fmaxf(sc[mt][0], sc[mt][1]), fmaxf(sc[mt][2], sc[mt][3]));
            v = fmaxf(v, __shfl_xor(v, 16));
            v = fmaxf(v, __shfl_xor(v, 32));
            mx[mt] = v;
        }
        #pragma unroll
        for (int mt = 0; mt < 4; ++mt) {
            float s = 0.f;
            #pragma unroll
            for (int r = 0; r < 4; ++r) {
                bool oob = (wv * 16 + quad * 4 + r) >= nv;
                float p = oob ? 0.f : __expf(sc[mt][r] - mx[mt]);
                sc[mt][r] = p;
                s += p;
            }
            s += __shfl_xor(s, 16);
            s += __shfl_xor(s, 32);
            sm[mt] = s;
        }
        if (quad == 0) {
            #pragma unroll
            for (int mt = 0; mt < 4; ++mt) {
                stat_mx[wv][mt * 16 + l15] = mx[mt];
                stat_sm[wv][mt * 16 + l15] = sm[mt];
            }
        }
        __syncthreads();  // C: stats visible; all M reads done
        // combine strips (redundant per wave)
        float fown[4];
        #pragma unroll
        for (int mt = 0; mt < 4; ++mt) {
            int qrow = mt * 16 + l15;
            float m0 = stat_mx[0][qrow], m1 = stat_mx[1][qrow];
            float m2 = stat_mx[2][qrow], m3 = stat_mx[3][qrow];
            float gmax = fmaxf(fmaxf(m0, m1), fmaxf(m2, m3));
            float mn = fmaxf(m_run[mt], gmax);
            float al = __expf(m_run[mt] - mn);
            float e0 = __expf(m0 - mn), e1 = __expf(m1 - mn);
            float e2 = __expf(m2 - mn), e3 = __expf(m3 - mn);
            l_run[mt] = l_run[mt] * al + stat_sm[0][qrow] * e0 + stat_sm[1][qrow] * e1
                      + stat_sm[2][qrow] * e2 + stat_sm[3][qrow] * e3;
            m_run[mt] = mn;
            fown[mt] = (wv == 0) ? e0 : (wv == 1) ? e1 : (wv == 2) ? e2 : e3;
            if (wv == 0 && quad == 0) alpha_s[qrow] = al;
        }
        // write P_adj bf16 -> Ps[query][key] swizzled
        #pragma unroll
        for (int mt = 0; mt < 4; ++mt) {
            int qrow = mt * 16 + l15;
            int base = qrow * 64;
            #pragma unroll
            for (int r = 0; r < 4; ++r) {
                int key = wv * 16 + quad * 4 + r;
                Ps[base + (((key >> 3) ^ (qrow & 7)) << 3) + (key & 7)] =
                    f2bf(sc[mt][r] * fown[mt]);
            }
        }
        // commit V(kt) from regs into MV (M region dead after C)
        #pragma unroll
        for (int it = 0; it < 8; ++it) {
            int u = it * 256 + tid;
            int ch = u >> 3, k8 = (u & 7) << 3;
            *(ushort8*)&MV[ch * 64 + (((k8 >> 3) ^ (ch & 7)) << 3)] = vpre[it];
        }
        // prefetch M(kt+1) (flies during PV)
        if (kt < 15) {
            int k0n = k0 + 64;
            int nvn = min(64, HW - k0n);
            #pragma unroll
            for (int it = 0; it < 8; ++it) {
                int v = it * 256 + tid;
                int key = v >> 5, ck = v & 31;
                ushort8 val = {0, 0, 0, 0, 0, 0, 0, 0};
                if (key < nvn)
                    val = *(const ushort8*)&Mbf[mbase + (size_t)(k0n + key) * 256 + ck * 8];
                mpre[it] = val;
            }
        }
        __syncthreads();  // D: Ps, V(kt), alpha visible
        // rescale O, then PV
        #pragma unroll
        for (int mt = 0; mt < 4; ++mt) {
            float al[4];
            #pragma unroll
            for (int r = 0; r < 4; ++r) al[r] = alpha_s[mt * 16 + quad * 4 + r];
            #pragma unroll
            for (int nt = 0; nt < 4; ++nt)
                #pragma unroll
                for (int r = 0; r < 4; ++r) o[mt][nt][r] *= al[r];
        }
        #pragma unroll
        for (int ks = 0; ks < 2; ++ks) {
            ushort8 af[4];
            #pragma unroll
            for (int mt = 0; mt < 4; ++mt) {
                int row = mt * 16 + l15;
                af[mt] = *(const ushort8*)&Ps[row * 64 + (((ks * 4 + quad) ^ (row & 7)) << 3)];
            }
            #pragma unroll
            for (int nt = 0; nt < 4; ++nt) {
                int ch = wv * 64 + nt * 16 + l15;
                ushort8 bv = *(const ushort8*)&MV[ch * 64 + (((ks * 4 + quad) ^ (ch & 7)) << 3)];
                #pragma unroll
                for (int mt = 0; mt < 4; ++mt)
                    o[mt][nt] = __builtin_amdgcn_mfma_f32_16x16x32_bf16(
                        __builtin_bit_cast(bf16x8, af[mt]),
                        __builtin_bit_cast(bf16x8, bv), o[mt][nt], 0, 0, 0);
            }
        }
        __syncthreads();  // E: PV's MV/Ps reads done
        if (kt < 15) {
            // commit M(kt+1); prefetch V(kt+1)
            #pragma unroll
            for (int it = 0; it < 8; ++it) {
                int v = it * 256 + tid;
                int key = v >> 5, ck = v & 31;
                *(ushort8*)&MV[key * 256 + ((ck ^ (key & 7)) << 3)] = mpre[it];
            }
            #pragma unroll
            for (int it = 0; it < 8; ++it) {
                int u = it * 256 + tid;
                int ch = u >> 3, k8 = (u & 7) << 3;
                vpre[it] = *(const ushort8*)&Vbf[vb + (size_t)ch * VP + k0 + 64 + k8];
            }
        }
        __syncthreads();  // F: M(kt+1) visible
    }
    // epilogue: final l across lane mappings
    if (wv == 0 && quad == 0) {
        #pragma unroll
        for (int mt = 0; mt < 4; ++mt) l_s[mt * 16 + l15] = l_run[mt];
    }
    __syncthreads();
    // write normalized O (bf16) into MV as [q][256ch]
    #pragma unroll
    for (int mt = 0; mt < 4; ++mt) {
        float invl[4];
        #pragma unroll
        for (int r = 0; r < 4; ++r) invl[r] = 1.f / l_s[mt * 16 + quad * 4 + r];
        #pragma unroll
        for (int nt = 0; nt < 4; ++nt) {
            int ch = wv * 64 + nt * 16 + l15;
            #pragma unroll
            for (int r = 0; r < 4; ++r) {
                int qrow = mt * 16 + quad * 4 + r;
                MV[qrow * 256 + ch] = f2bf(o[mt][nt][r] * invl[r]);
            }
        }
    }
    __syncthreads();
    // coalesced nontemporal store: 8 chunks/thread, 16B/lane
    #pragma unroll
    for (int k = 0; k < 8; ++k) {
        int idx = k * 256 + tid;
        int qrow = idx >> 5, c = idx & 31;
        int q = q0 + qrow;
        if (q < THW) {
            ushort8 v = *(const ushort8*)&MV[qrow * 256 + c * 8];
            __builtin_nontemporal_store(v,
                (ushort8*)&Rbf[((size_t)bm * THW + q) * 256 + c * 8]);
        }
    }
}

// ---------------- K5: compare convs via MFMA (R now bf16) ----------------
__global__ __launch_bounds__(256) void k_cmp(
    const unsigned short* __restrict__ Rbf, const float* __restrict__ Vcl,
    const unsigned short* __restrict__ Wpk, float* __restrict__ Pc) {
    __shared__ unsigned short Ws[24576] __attribute__((aligned(16)));  // 48 KB
    const int strip = blockIdx.x;
    const int s = blockIdx.y;
    const int b = blockIdx.z >> 1, kind = blockIdx.z & 1;
    const int m = s >> 2, tq = s & 3;
    const int tid = threadIdx.x;
    const int wv = tid >> 6, lane = tid & 63;
    const int l15 = lane & 15, quad = lane >> 4;

    const unsigned short* wsrc = Wpk + (kind ? 24576 : 0);
    for (int i = tid; i < 3072; i += 256) {
        int row, ch, stride_us;
        if (kind == 0) { row = i >> 6; ch = i & 63; stride_us = 512; }
        else           { row = i >> 5; ch = i & 31; stride_us = 256; }
        ushort8 v = *(const ushort8*)&wsrc[i * 8];
        *(ushort8*)&Ws[row * stride_us + ((ch ^ (row & 7)) << 3)] = v;
    }
    __syncthreads();

    const size_t rbase = ((size_t)(b * 4 + m) * THW + tq * HW) * 256;
    const size_t vbase = ((size_t)b * THW + m * HW) * 256;

    #pragma unroll
    for (int half = 0; half < 2; ++half) {
        int pxt = wv * 2 + half;
        int hw = strip * 128 + pxt * 16 + l15;
        int hwc = min(hw, HW - 1);
        const unsigned short* rrow = Rbf + rbase + (size_t)hwc * 256;
        const float* vrow = Vcl + vbase + (size_t)hwc * 256;
        bf16x8 fr[8], fs[8];   // kind0: R,V ; kind1: D,P
        #pragma unroll
        for (int ks = 0; ks < 8; ++ks) {
            ushort8 r8 = *(const ushort8*)&rrow[ks * 32 + quad * 8];
            float vv[8];
            *(float4*)&vv[0] = *(const float4*)&vrow[ks * 32 + quad * 8];
            *(float4*)&vv[4] = *(const float4*)&vrow[ks * 32 + quad * 8 + 4];
            bf16x8 a, c;
            if (kind == 0) {
                a = __builtin_bit_cast(bf16x8, r8);
                #pragma unroll
                for (int j = 0; j < 8; ++j) c[j] = (__bf16)vv[j];
            } else {
                #pragma unroll
                for (int j = 0; j < 8; ++j) {
                    float rj = bf2f(r8[j]);
                    a[j] = (__bf16)(rj - vv[j]);
                    c[j] = (__bf16)(rj * vv[j]);
                }
            }
            fr[ks] = a; fs[ks] = c;
        }
        floatx4 acc[6];
        #pragma unroll
        for (int i = 0; i < 6; ++i) acc[i] = (floatx4){0.f, 0.f, 0.f, 0.f};
        if (kind == 0) {
            #pragma unroll
            for (int ks = 0; ks < 16; ++ks) {
                bf16x8 bfr = (ks < 8) ? fr[ks] : fs[ks - 8];
                #pragma unroll
                for (int cit = 0; cit < 3; ++cit) {
                    int row = cit * 16 + l15;
                    ushort8 aw = *(const ushort8*)&Ws[row * 512 + (((ks * 4 + quad) ^ (row & 7)) << 3)];
                    acc[cit] = __builtin_amdgcn_mfma_f32_16x16x32_bf16(
                        __builtin_bit_cast(bf16x8, aw), bfr, acc[cit], 0, 0, 0);
                }
            }
        } else {
            #pragma unroll
            for (int ks = 0; ks < 8; ++ks) {
                #pragma unroll
                for (int cit = 0; cit < 6; ++cit) {
                    int row = cit * 16 + l15;
                    ushort8 aw = *(const ushort8*)&Ws[row * 256 + (((ks * 4 + quad) ^ (row & 7)) << 3)];
                    bf16x8 bfr = (cit < 3) ? fr[ks] : fs[ks];
                    acc[cit] = __builtin_amdgcn_mfma_f32_16x16x32_bf16(
                        __builtin_bit_cast(bf16x8, aw), bfr, acc[cit], 0, 0, 0);
                }
            }
        }
        if (hw < HW) {
            if (kind == 0) {
                #pragma unroll
                for (int cit = 0; cit < 3; ++cit)
                    #pragma unroll
                    for (int r = 0; r < 4; ++r) {
                        int ci = cit * 16 + quad * 4 + r;
                        if (ci < 42)
                            Pc[((size_t)(b * NCMP + ci) * 16 + s) * HW + hw] = acc[cit][r];
                    }
            } else {
                #pragma unroll
                for (int cit = 0; cit < 6; ++cit)
                    #pragma unroll
                    for (int r = 0; r < 4; ++r) {
                        int cl = (cit % 3) * 16 + quad * 4 + r;
                        if (cl < 42) {
                            int ci = (cit < 3 ? 42 : 84) + cl;
                            Pc[((size_t)(b * NCMP + ci) * 16 + s) * HW + hw] = acc[cit][r];
                        }
                    }
            }
        }
    }
}

// ---------------- K6: BN stats for compare ----------------
__global__ __launch_bounds__(256) void k_stats_cmp(
    const float* __restrict__ Pc, const float* __restrict__ g_cat,
    const float* __restrict__ b_cat, const float* __restrict__ g_sub,
    const float* __restrict__ b_sub, const float* __restrict__ g_mul,
    const float* __restrict__ b_mul, float* __restrict__ bnc) {
    const int c = blockIdx.x, tid = threadIdx.x;
    float s = 0.f, q = 0.f;
    for (int i = tid; i < 4 * 16 * HW; i += 256) {
        int bb = i / (16 * HW), r = i - bb * (16 * HW);
        float v = Pc[(size_t)(bb * NCMP + c) * (16 * HW) + r];
        s += v; q += v * v;
    }
    __shared__ float rs[256], rq[256];
    rs[tid] = s; rq[tid] = q;
    __syncthreads();
    for (int off = 128; off > 0; off >>= 1) {
        if (tid < off) { rs[tid] += rs[tid + off]; rq[tid] += rq[tid + off]; }
        __syncthreads();
    }
    if (tid == 0) {
        const float n = 4.f * 16.f * HW;
        float mean = rs[0] / n;
        float var = rq[0] / n - mean * mean;
        float g, bt;
        if (c < 42)       { g = g_cat[c];      bt = b_cat[c]; }
        else if (c < 84)  { g = g_sub[c - 42]; bt = b_sub[c - 42]; }
        else              { g = g_mul[c - 84]; bt = b_mul[c - 84]; }
        float sc = g * rsqrtf(var + BN_EPS);
        bnc[c] = sc;
        bnc[NCMP + c] = bt - mean * sc;
    }
}

// ---------------- K7: build Y channel-last bf16 [b][p][1024] ----------------
__global__ __launch_bounds__(256) void k_build_y(
    const unsigned short* __restrict__ Rbf, const float* __restrict__ Vcl,
    const float* __restrict__ Pc, const float* __restrict__ bnc,
    unsigned short* __restrict__ Ybf) {
    const int strip = blockIdx.x, t = blockIdx.y, b = blockIdx.z;
    const int tid = threadIdx.x;
    const int chl = tid & 31;
    const int hwl = tid >> 5;
    for (int pass = 0; pass < 8; ++pass) {
        int hw = strip * 64 + pass * 8 + hwl;
        if (hw >= HW) continue;
        size_t ybase = ((size_t)b * THW + t * HW + hw) * 1024;
        for (int cb = 0; cb < 8; ++cb) {
            int ch = cb * 128 + chl * 4;
            float v[4];
            if (ch < 256) {
                v[0] = v[1] = v[2] = v[3] = 0.f;
                #pragma unroll
                for (int tq = 0; tq < 4; ++tq) {
                    ushort4v rv = *(const ushort4v*)&Rbf[
                        (((size_t)(b * 4 + t)) * THW + tq * HW + hw) * 256 + ch];
                    v[0] += bf2f(rv[0]); v[1] += bf2f(rv[1]);
                    v[2] += bf2f(rv[2]); v[3] += bf2f(rv[3]);
                }
                v[0] *= 0.25f; v[1] *= 0.25f; v[2] *= 0.25f; v[3] *= 0.25f;
            } else if (ch < 512) {
                float4 vv = *(const float4*)&Vcl[((size_t)b * THW + t * HW + hw) * 256 + (ch - 256)];
                v[0] = vv.x; v[1] = vv.y; v[2] = vv.z; v[3] = vv.w;
            } else if (ch < 1016) {
                int ci = (ch - 512) >> 2;
                float sc = bnc[ci], sh = bnc[NCMP + ci];
                #pragma unroll
                for (int mm = 0; mm < 4; ++mm) {
                    float pv = Pc[(((size_t)(b * NCMP + ci)) * 16 + mm * 4 + t) * HW + hw];
                    v[mm] = fmaxf(fmaf(pv, sc, sh), 0.f);
                }
            } else {
                v[0] = v[1] = v[2] = v[3] = 0.f;
            }
            ushort4v ov;
            #pragma unroll
            for (int i = 0; i < 4; ++i) ov[i] = f2bf(v[i]);
            *(ushort4v*)&Ybf[ybase + ch] = ov;
        }
    }
}

// ---------------- K8: aggregate GEMM via MFMA ----------------
__global__ __launch_bounds__(256) void k_aggm(
    const unsigned short* __restrict__ Wab, const unsigned short* __restrict__ Ybf,
    float* __restrict__ Z) {
    __shared__ unsigned short Wt[16384] __attribute__((aligned(16)));
    const int p0 = blockIdx.x * 128;
    const int oc0 = blockIdx.y * 128;
    const int b = blockIdx.z;
    const int tid = threadIdx.x;
    const int wv = tid >> 6, lane = tid & 63;
    const int l15 = lane & 15, quad = lane >> 4;
    floatx4 acc[8][2];
    #pragma unroll
    for (int i = 0; i < 8; ++i)
        #pragma unroll
        for (int h = 0; h < 2; ++h) acc[i][h] = (floatx4){0.f, 0.f, 0.f, 0.f};
    for (int kc = 0; kc < 8; ++kc) {
        __syncthreads();
        for (int i = tid; i < 2048; i += 256) {
            int row = i >> 4, ch = i & 15;
            ushort8 v = *(const ushort8*)&Wab[(size_t)(oc0 + row) * 1024 + kc * 128 + ch * 8];
            *(ushort8*)&Wt[row * 128 + ((ch ^ (row & 7)) << 3)] = v;
        }
        __syncthreads();
        #pragma unroll
        for (int half = 0; half < 2; ++half) {
            int px = p0 + (wv * 2 + half) * 16 + l15;
            int pxc = min(px, THW - 1);
            const unsigned short* yrow = Ybf + ((size_t)b * THW + pxc) * 1024 + kc * 128;
            #pragma unroll
            for (int ks = 0; ks < 4; ++ks) {
                ushort8 bf = *(const ushort8*)&yrow[ks * 32 + quad * 8];
                #pragma unroll
                for (int oct = 0; oct < 8; ++oct) {
                    int row = oct * 16 + l15;
                    ushort8 af = *(const ushort8*)&Wt[row * 128 + ((((ks * 4 + quad) ^ (row & 7))) << 3)];
                    acc[oct][half] = __builtin_amdgcn_mfma_f32_16x16x32_bf16(
                        __builtin_bit_cast(bf16x8, af),
                        __builtin_bit_cast(bf16x8, bf), acc[oct][half], 0, 0, 0);
                }
            }
        }
    }
    #pragma unroll
    for (int half = 0; half < 2; ++half) {
        int px = p0 + (wv * 2 + half) * 16 + l15;
        if (px < THW) {
            #pragma unroll
            for (int oct = 0; oct < 8; ++oct) {
                int oc = oc0 + oct * 16 + quad * 4;
                #pragma unroll
                for (int r = 0; r < 4; ++r)
                    Z[((size_t)(b * Cch + oc + r)) * THW + px] = acc[oct][half][r];
            }
        }
    }
}

// ---------------- K9: BN stats for aggregate ----------------
__global__ __launch_bounds__(256) void k_stats_agg(
    const float* __restrict__ Z, const float* __restrict__ g_agg,
    const float* __restrict__ b_agg, float* __restrict__ bna) {
    const int c = blockIdx.x, tid = threadIdx.x;
    float s = 0.f, q = 0.f;
    for (int i = tid; i < 4 * THW; i += 256) {
        int bb = i / THW, p = i - bb * THW;
        float v = Z[((size_t)bb * Cch + c) * THW + p];
        s += v; q += v * v;
    }
    __shared__ float rs[256], rq[256];
    rs[tid] = s; rq[tid] = q;
    __syncthreads();
    for (int off = 128; off > 0; off >>= 1) {
        if (tid < off) { rs[tid] += rs[tid + off]; rq[tid] += rq[tid + off]; }
        __syncthreads();
    }
    if (tid == 0) {
        const float n = 4.f * THW;
        float mean = rs[0] / n;
        float var = rq[0] / n - mean * mean;
        float sc = g_agg[c] * rsqrtf(var + BN_EPS);
        bna[c] = sc;
        bna[Cch + c] = b_agg[c] - mean * sc;
    }
}

// ---------------- K10: out = relu(xp + BN(Z)) ----------------
__global__ __launch_bounds__(256) void k_final(const float* __restrict__ xp,
                                               const float* __restrict__ Z,
                                               const float* __restrict__ bna,
                                               float* __restrict__ out) {
    int idx = blockIdx.x * 256 + threadIdx.x;
    if (idx >= NPIX) return;
    int c = (idx / THW) & 511;
    out[idx] = fmaxf(fmaf(Z[idx], bna[c], bna[Cch + c]) + xp[idx], 0.f);
}

extern "C" void kernel_launch(void* const* d_in, const int* in_sizes, int n_in,
                              void* d_out, int out_size, void* d_ws, size_t ws_size,
                              hipStream_t stream) {
    const float* x     = (const float*)d_in[0];
    const float* Wq    = (const float*)d_in[1];
    const float* Wm    = (const float*)d_in[2];
    const float* Wv    = (const float*)d_in[3];
    const float* Wcat  = (const float*)d_in[4];
    const float* Wsub  = (const float*)d_in[5];
    const float* Wmul  = (const float*)d_in[6];
    const float* g_cat = (const float*)d_in[7];
    const float* b_cat = (const float*)d_in[8];
    const float* g_sub = (const float*)d_in[9];
    const float* b_sub = (const float*)d_in[10];
    const float* g_mul = (const float*)d_in[11];
    const float* b_mul = (const float*)d_in[12];
    const float* Wagg  = (const float*)d_in[13];
    const float* g_agg = (const float*)d_in[14];
    const float* b_agg = (const float*)d_in[15];
    float* out = (float*)d_out;
    float* ws  = (float*)d_ws;

    // workspace layout (float offsets); total 35,714,560 fl = 142.9 MB
    float* xp  = ws;                          // 7,872,512
    float* Vcl = xp + 7872512;                // 3,936,256  -> 11,808,768
    float* bnc = Vcl + 3936256;               // 512        -> 11,809,280
    float* bna = bnc + 512;                   // 1024       -> 11,810,304
    unsigned short* Wpk = (unsigned short*)(bna + 1024);   // 49,152 us = 24,576 fl
    unsigned short* Wab = Wpk + 49152;                     // 524,288 us = 262,144 fl
    float* bfreg = (float*)(Wab + 524288);    // 7,872,512 fl -> Qbf/Mbf/Vbf; later Ybf
    unsigned short* Qbf = (unsigned short*)bfreg;          // 3,936,256 us
    unsigned short* Mbf = Qbf + 3936256;                   // 3,936,256 us
    unsigned short* Vbf = Mbf + 3936256;                   // 4,194,304 us
    unsigned short* Ybf = (unsigned short*)bfreg;          // alias (Q/M/V dead)
    unsigned short* Rbf = (unsigned short*)(bfreg + 7872512);  // 15,745,024 us = 7,872,512 fl
    float* Pc = (float*)(Rbf + 15745024);     // 7,750,656 fl (+121,856 pad for Z tail)
    float* Z  = (float*)Rbf;                  // alias: Rbf+Pc dead after build_y

    k_prep_w<<<dim3(2240), dim3(256), 0, stream>>>(Wcat, Wsub, Wmul, Wagg, Wpk, Wab);
    k_pool<<<dim3((NPIX + 255) / 256), dim3(256), 0, stream>>>(x, xp);
    k_qmv<<<dim3(61, 12, Bb), dim3(16, 16), 0, stream>>>(xp, Wq, Wm, Wv, Qbf, Mbf,
                                                         Vcl, Vbf);
    k_attn_mfma<<<dim3(16, 61), dim3(256), 0, stream>>>(Qbf, Mbf, Vbf, Rbf);
    k_cmp<<<dim3(8, 16, 8), dim3(256), 0, stream>>>(Rbf, Vcl, Wpk, Pc);
    k_stats_cmp<<<dim3(NCMP), dim3(256), 0, stream>>>(Pc, g_cat, b_cat, g_sub, b_sub,
                                                      g_mul, b_mul, bnc);
    k_build_y<<<dim3(16, 4, Bb), dim3(256), 0, stream>>>(Rbf, Vcl, Pc, bnc, Ybf);
    k_aggm<<<dim3(31, 4, Bb), dim3(256), 0, stream>>>(Wab, Ybf, Z);
    k_stats_agg<<<dim3(Cch), dim3(256), 0, stream>>>(Z, g_agg, b_agg, bna);
    k_final<<<dim3((NPIX + 255) / 256), dim3(256), 0, stream>>>(xp, Z, bna, out);
}